// Round 4
// baseline (208.387 us; speedup 1.0000x reference)
//
#include <hip/hip_runtime.h>
#include <hip/hip_bf16.h>
#include <math.h>

#define S_LEN 2048
#define FDIM  512
#define NH    8
#define HD    64
#define MH_ELEMS (S_LEN * FDIM)          // 1048576
#define MEAN_ELEMS (S_LEN * S_LEN)       // 4194304

typedef _Float16 half_t;
typedef _Float16 half2v __attribute__((ext_vector_type(2)));
typedef _Float16 half8v __attribute__((ext_vector_type(8)));
typedef float    float4v __attribute__((ext_vector_type(4)));

#define MFMA16(a, b, c) __builtin_amdgcn_mfma_f32_16x16x32_f16((a), (b), (c), 0, 0, 0)

#define PS2 264   // Ps stride in halves (528B rows): b128-aligned, measured-fine bank pattern

// ---------------- Kernel 1: LayerNorm + PE row 0 -> f16 ----------------
__global__ __launch_bounds__(256) void ln_pe_kernel(const float* __restrict__ x,
                                                    const float* __restrict__ gamma,
                                                    const float* __restrict__ beta,
                                                    half_t* __restrict__ xo) {
    const int row = blockIdx.x;
    const int tid = threadIdx.x;
    const float2 v = ((const float2*)(x + (size_t)row * FDIM))[tid];
    float s = v.x + v.y;
    float q = v.x * v.x + v.y * v.y;
    #pragma unroll
    for (int off = 1; off < 64; off <<= 1) {
        s += __shfl_xor(s, off, 64);
        q += __shfl_xor(q, off, 64);
    }
    __shared__ float red[8];
    const int wave = tid >> 6;
    if ((tid & 63) == 0) { red[wave] = s; red[4 + wave] = q; }
    __syncthreads();
    s = red[0] + red[1] + red[2] + red[3];
    q = red[4] + red[5] + red[6] + red[7];
    const float mu  = s * (1.0f / FDIM);
    const float var = q * (1.0f / FDIM) - mu * mu;
    const float rstd = rsqrtf(var + 1e-5f);
    const int f0 = tid * 2, f1 = tid * 2 + 1;
    const float o0 = (v.x - mu) * rstd * gamma[f0] + beta[f0];
    const float o1 = (v.y - mu) * rstd * gamma[f1] + beta[f1] + 1.0f;
    half2v o; o.x = (half_t)o0; o.y = (half_t)o1;
    ((half2v*)(xo + (size_t)row * FDIM))[tid] = o;
}

// ---------------- Kernel 2: W -> W^T f16  (WT[z][h][d][k]) ----------------
// grid = (8 k-tiles of 64, 8 heads, 3 z). fp32 LDS transpose, conflict-free.
__global__ __launch_bounds__(256) void wt_kernel(const float* __restrict__ Wq,
                                                 const float* __restrict__ Wk,
                                                 const float* __restrict__ Wv,
                                                 half_t* __restrict__ WT) {
    const int k0 = blockIdx.x * 64;
    const int h  = blockIdx.y, z = blockIdx.z;
    const float* W = ((z == 0) ? Wq : (z == 1) ? Wk : Wv) + (size_t)h * FDIM * HD;
    __shared__ float Ls[64][65];
    const int tid = threadIdx.x;
    {
        const int kk = tid >> 2, dg = (tid & 3) * 16;
        #pragma unroll
        for (int j = 0; j < 4; ++j) {
            const float4 w = *(const float4*)(W + (size_t)(k0 + kk) * HD + dg + j * 4);
            Ls[kk][dg + j * 4 + 0] = w.x; Ls[kk][dg + j * 4 + 1] = w.y;
            Ls[kk][dg + j * 4 + 2] = w.z; Ls[kk][dg + j * 4 + 3] = w.w;
        }
    }
    __syncthreads();
    {
        const int d = tid >> 2, kg = (tid & 3) * 16;
        half8v t0, t1;
        #pragma unroll
        for (int j = 0; j < 8; ++j) t0[j] = (half_t)Ls[kg + j][d];
        #pragma unroll
        for (int j = 0; j < 8; ++j) t1[j] = (half_t)Ls[kg + 8 + j][d];
        half_t* dst = WT + ((size_t)(z * NH + h) * HD + d) * FDIM + k0 + kg;
        *(half8v*)dst = t0;
        *(half8v*)(dst + 8) = t1;
    }
}

// ---------------- Kernel 3: QKV projections, LDS-free MFMA; V written transposed ----------------
// grid = (32 m-tiles of 64, 8 heads, 3 z)
__global__ __launch_bounds__(256) void qkv_kernel(const half_t* __restrict__ xh,
                                                  const half_t* __restrict__ WT,
                                                  half_t* __restrict__ Qo,
                                                  half_t* __restrict__ Ko,
                                                  half_t* __restrict__ VTo) {
    const int ms0 = blockIdx.x * 64;
    const int h   = blockIdx.y, z = blockIdx.z;
    const half_t* Wt = WT + (size_t)(z * NH + h) * HD * FDIM;   // [64][512] = W^T

    const int tid = threadIdx.x;
    const int wv = tid >> 6, lane = tid & 63;
    const int lo = lane & 15, qq = lane >> 4;

    float4v acc[4];
    #pragma unroll
    for (int cg = 0; cg < 4; ++cg) acc[cg] = (float4v){0.f, 0.f, 0.f, 0.f};

    for (int k0 = 0; k0 < FDIM; k0 += 32) {
        const half8v a = *(const half8v*)(xh + (size_t)(ms0 + wv * 16 + lo) * FDIM + k0 + qq * 8);
        half8v b[4];
        #pragma unroll
        for (int cg = 0; cg < 4; ++cg)
            b[cg] = *(const half8v*)(Wt + (size_t)(cg * 16 + lo) * FDIM + k0 + qq * 8);
        #pragma unroll
        for (int cg = 0; cg < 4; ++cg) acc[cg] = MFMA16(a, b[cg], acc[cg]);
    }

    __shared__ float Ls[64][65];
    if (z < 2) {
        half_t* Co = ((z == 0) ? Qo : Ko) + (size_t)h * S_LEN * HD;
        #pragma unroll
        for (int cg = 0; cg < 4; ++cg)
            #pragma unroll
            for (int r = 0; r < 4; ++r)
                Co[(size_t)(ms0 + wv * 16 + qq * 4 + r) * HD + cg * 16 + lo] = (half_t)acc[cg][r];
    } else {
        // transpose 64x64 tile through LDS, write VT[h][d][s]
        #pragma unroll
        for (int cg = 0; cg < 4; ++cg)
            #pragma unroll
            for (int r = 0; r < 4; ++r)
                Ls[wv * 16 + qq * 4 + r][cg * 16 + lo] = acc[cg][r];
        __syncthreads();
        const int d = tid & 63, sg = tid >> 6;
        half8v t0, t1;
        #pragma unroll
        for (int j = 0; j < 8; ++j) t0[j] = (half_t)Ls[sg * 16 + j][d];
        #pragma unroll
        for (int j = 0; j < 8; ++j) t1[j] = (half_t)Ls[sg * 16 + 8 + j][d];
        half_t* dst = VTo + (size_t)(h * HD + d) * S_LEN + ms0 + sg * 16;
        *(half8v*)dst = t0;
        *(half8v*)(dst + 8) = t1;
    }
}

// ---------------- Kernel 4: softmax denominators (no-max) -> 1/l ----------------
__global__ __launch_bounds__(256) void lsum_kernel(const half_t* __restrict__ Qw,
                                                   const half_t* __restrict__ Kw,
                                                   float* __restrict__ linv) {
    const int s0 = blockIdx.x * 16;
    const int h  = blockIdx.y;
    const half_t* Qh = Qw + (size_t)h * S_LEN * HD;
    const half_t* Kh = Kw + (size_t)h * S_LEN * HD;

    const int tid = threadIdx.x;
    const int wv = tid >> 6, lane = tid & 63;
    const int lo = lane & 15, qq = lane >> 4;

    const half8v aq0 = *(const half8v*)(Qh + (size_t)(s0 + lo) * HD + qq * 8);
    const half8v aq1 = *(const half8v*)(Qh + (size_t)(s0 + lo) * HD + 32 + qq * 8);

    float esum[4] = {0.f, 0.f, 0.f, 0.f};
    #pragma unroll 2
    for (int j = 0; j < 32; ++j) {
        const int cbase = (wv + 4 * j) * 16;
        const half8v b0 = *(const half8v*)(Kh + (size_t)(cbase + lo) * HD + qq * 8);
        const half8v b1 = *(const half8v*)(Kh + (size_t)(cbase + lo) * HD + 32 + qq * 8);
        float4v c4 = {0.f, 0.f, 0.f, 0.f};
        c4 = MFMA16(aq0, b0, c4);
        c4 = MFMA16(aq1, b1, c4);
        const int dd0 = cbase - s0;
        const bool near = (dd0 > -24) && (dd0 < 24);
        #pragma unroll
        for (int r = 0; r < 4; ++r) {
            float s = c4[r] * 0.125f;
            if (near) {
                const float d = (float)(s0 + qq * 4 + r - cbase - lo);
                s += __expf(-0.5f * d * d);
            }
            s = fminf(s, 60.f);
            esum[r] += __expf(s);
        }
    }
    #pragma unroll
    for (int r = 0; r < 4; ++r) {
        #pragma unroll
        for (int mk = 1; mk < 16; mk <<= 1) esum[r] += __shfl_xor(esum[r], mk, 64);
    }
    __shared__ float red[4][16];
    if (lo == 0) {
        #pragma unroll
        for (int r = 0; r < 4; ++r) red[wv][qq * 4 + r] = esum[r];
    }
    __syncthreads();
    if (tid < 16) {
        const float l = red[0][tid] + red[1][tid] + red[2][tid] + red[3][tid];
        linv[(size_t)h * S_LEN + s0 + tid] = 1.0f / l;
    }
}

// ---------------- Kernel 5: attention, 512 threads, heads-in-block ----------------
// grid = (64 q-tiles of 32 rows, 8 col-chunks of 256). 8 waves: rg=wv&1, cq=wv>>1.
__global__ __launch_bounds__(512, 4) void attn_kernel(const half_t* __restrict__ Qw,
                                                      const half_t* __restrict__ Kw,
                                                      const half_t* __restrict__ VT,
                                                      const float* __restrict__ linv,
                                                      half_t* __restrict__ partial,
                                                      float* __restrict__ out) {
    const int s0 = blockIdx.x * 32;
    const int c0 = blockIdx.y * 256;

    __shared__ half_t Ps[32 * PS2];   // 16.9 KB

    const int tid = threadIdx.x;
    const int wv = tid >> 6, lane = tid & 63;
    const int rg = wv & 1, cq = wv >> 1;          // cq: col quarter (QK) / d quarter (PV)
    const int lo = lane & 15, qq = lane >> 4;
    const int rbase = s0 + rg * 16;

    float msum[4][4];
    #pragma unroll
    for (int ct = 0; ct < 4; ++ct)
        #pragma unroll
        for (int r = 0; r < 4; ++r) msum[ct][r] = 0.f;

    half_t* po = partial + (size_t)blockIdx.y * (size_t)MH_ELEMS;

    for (int h = 0; h < NH; ++h) {
        const half_t* Qh = Qw + (size_t)h * S_LEN * HD;
        const half_t* Kh = Kw + (size_t)h * S_LEN * HD;
        const half_t* Vt = VT + (size_t)h * (size_t)HD * S_LEN;
        __syncthreads();   // prev head's Ps readers done
        const half8v aq0 = *(const half8v*)(Qh + (size_t)(rbase + lo) * HD + qq * 8);
        const half8v aq1 = *(const half8v*)(Qh + (size_t)(rbase + lo) * HD + 32 + qq * 8);
        float li[4];
        #pragma unroll
        for (int r = 0; r < 4; ++r) li[r] = linv[(size_t)h * S_LEN + rbase + qq * 4 + r];
        #pragma unroll
        for (int ct = 0; ct < 4; ++ct) {
            const int cbase = c0 + cq * 64 + ct * 16;
            const half8v b0 = *(const half8v*)(Kh + (size_t)(cbase + lo) * HD + qq * 8);
            const half8v b1 = *(const half8v*)(Kh + (size_t)(cbase + lo) * HD + 32 + qq * 8);
            float4v c4 = {0.f, 0.f, 0.f, 0.f};
            c4 = MFMA16(aq0, b0, c4);
            c4 = MFMA16(aq1, b1, c4);
            const int dd0 = cbase - rbase;
            const bool near = (dd0 > -24) && (dd0 < 24);
            #pragma unroll
            for (int r = 0; r < 4; ++r) {
                float s = c4[r] * 0.125f;
                if (near) {
                    const float d = (float)(rbase + qq * 4 + r - cbase - lo);
                    s += __expf(-0.5f * d * d);
                }
                s = fminf(s, 60.f);
                const float p = __expf(s) * li[r];
                msum[ct][r] += p;
                Ps[(size_t)(rg * 16 + qq * 4 + r) * PS2 + cq * 64 + ct * 16 + lo] = (half_t)p;
            }
        }
        __syncthreads();   // Ps complete
        float4v accO = {0.f, 0.f, 0.f, 0.f};
        #pragma unroll
        for (int ks = 0; ks < 8; ++ks) {
            const half8v ap = *(const half8v*)&Ps[(size_t)(rg * 16 + lo) * PS2 + ks * 32 + qq * 8];
            const half8v bv = *(const half8v*)(Vt + (size_t)(cq * 16 + lo) * S_LEN + c0 + ks * 32 + qq * 8);
            accO = MFMA16(ap, bv, accO);
        }
        #pragma unroll
        for (int r = 0; r < 4; ++r)
            po[(size_t)(rbase + qq * 4 + r) * FDIM + h * HD + cq * 16 + lo] = (half_t)accO[r];
    }
    // mean_weights written directly (fp32)
    #pragma unroll
    for (int ct = 0; ct < 4; ++ct)
        #pragma unroll
        for (int r = 0; r < 4; ++r)
            out[MH_ELEMS + (size_t)(rbase + qq * 4 + r) * S_LEN + c0 + cq * 64 + ct * 16 + lo] =
                msum[ct][r] * 0.125f;
}

// ---------------- Kernel 6: reduce 8 f16 chunk-partials -> multi_head_output ----------------
__global__ __launch_bounds__(256) void reduce_kernel(const half_t* __restrict__ partial,
                                                     float* __restrict__ out) {
    const size_t i8 = ((size_t)blockIdx.x * 256 + threadIdx.x) * 8;
    float s[8] = {0.f, 0.f, 0.f, 0.f, 0.f, 0.f, 0.f, 0.f};
    #pragma unroll
    for (int c = 0; c < 8; ++c) {
        const half8v t = *(const half8v*)(partial + (size_t)c * MH_ELEMS + i8);
        #pragma unroll
        for (int j = 0; j < 8; ++j) s[j] += (float)t[j];
    }
    *(float4*)(out + i8)     = make_float4(s[0], s[1], s[2], s[3]);
    *(float4*)(out + i8 + 4) = make_float4(s[4], s[5], s[6], s[7]);
}

extern "C" void kernel_launch(void* const* d_in, const int* in_sizes, int n_in,
                              void* d_out, int out_size, void* d_ws, size_t ws_size,
                              hipStream_t stream) {
    const float* x  = (const float*)d_in[0];
    const float* Wq = (const float*)d_in[1];
    const float* Wk = (const float*)d_in[2];
    const float* Wv = (const float*)d_in[3];
    const float* g  = (const float*)d_in[4];
    const float* b  = (const float*)d_in[5];
    float* out = (float*)d_out;
    char*  ws  = (char*)d_ws;

    half_t* xh   = (half_t*)(ws);                   // 2 MB
    half_t* Qh   = (half_t*)(ws + (2ull  << 20));   // 2 MB
    half_t* Kh   = (half_t*)(ws + (4ull  << 20));   // 2 MB
    half_t* VT   = (half_t*)(ws + (6ull  << 20));   // 2 MB   [8][64][2048]
    half_t* WT   = (half_t*)(ws + (8ull  << 20));   // 1.5 MB [3][8][64][512]
    float*  linv = (float*) (ws + (10ull << 20));   // 64 KB
    half_t* part = (half_t*)(ws + (11ull << 20));   // 16 MB  [8][1M] f16

    ln_pe_kernel<<<S_LEN, 256, 0, stream>>>(x, g, b, xh);
    wt_kernel<<<dim3(8, 8, 3), 256, 0, stream>>>(Wq, Wk, Wv, WT);
    qkv_kernel<<<dim3(32, 8, 3), 256, 0, stream>>>(xh, WT, Qh, Kh, VT);
    lsum_kernel<<<dim3(128, 8), 256, 0, stream>>>(Qh, Kh, linv);
    attn_kernel<<<dim3(64, 8), 512, 0, stream>>>(Qh, Kh, VT, linv, part, out);
    reduce_kernel<<<MH_ELEMS / 8 / 256, 256, 0, stream>>>(part, out);
}

// Round 5
// 205.516 us; speedup vs baseline: 1.0140x; 1.0140x over previous
//
#include <hip/hip_runtime.h>
#include <hip/hip_bf16.h>
#include <math.h>

#define S_LEN 2048
#define FDIM  512
#define NH    8
#define HD    64
#define MH_ELEMS (S_LEN * FDIM)          // 1048576
#define MEAN_ELEMS (S_LEN * S_LEN)       // 4194304

typedef _Float16 half_t;
typedef _Float16 half2v __attribute__((ext_vector_type(2)));
typedef _Float16 half8v __attribute__((ext_vector_type(8)));
typedef float    float4v __attribute__((ext_vector_type(4)));

#define MFMA16(a, b, c) __builtin_amdgcn_mfma_f32_16x16x32_f16((a), (b), (c), 0, 0, 0)

#define PS2 264   // Ps stride in halves (528B rows)

// lgkmcnt(0), vmcnt=max(63), expcnt=max(7): wait LDS only, leave global loads in flight
#define LDS_ONLY_WAITCNT 0xC07F

// ---------------- Kernel 1: LayerNorm + PE row 0 -> f16 ----------------
__global__ __launch_bounds__(256) void ln_pe_kernel(const float* __restrict__ x,
                                                    const float* __restrict__ gamma,
                                                    const float* __restrict__ beta,
                                                    half_t* __restrict__ xo) {
    const int row = blockIdx.x;
    const int tid = threadIdx.x;
    const float2 v = ((const float2*)(x + (size_t)row * FDIM))[tid];
    float s = v.x + v.y;
    float q = v.x * v.x + v.y * v.y;
    #pragma unroll
    for (int off = 1; off < 64; off <<= 1) {
        s += __shfl_xor(s, off, 64);
        q += __shfl_xor(q, off, 64);
    }
    __shared__ float red[8];
    const int wave = tid >> 6;
    if ((tid & 63) == 0) { red[wave] = s; red[4 + wave] = q; }
    __syncthreads();
    s = red[0] + red[1] + red[2] + red[3];
    q = red[4] + red[5] + red[6] + red[7];
    const float mu  = s * (1.0f / FDIM);
    const float var = q * (1.0f / FDIM) - mu * mu;
    const float rstd = rsqrtf(var + 1e-5f);
    const int f0 = tid * 2, f1 = tid * 2 + 1;
    const float o0 = (v.x - mu) * rstd * gamma[f0] + beta[f0];
    const float o1 = (v.y - mu) * rstd * gamma[f1] + beta[f1] + 1.0f;
    half2v o; o.x = (half_t)o0; o.y = (half_t)o1;
    ((half2v*)(xo + (size_t)row * FDIM))[tid] = o;
}

// ---------------- Kernel 2: W -> W^T f16  (WT[z][h][d][k]) ----------------
__global__ __launch_bounds__(256) void wt_kernel(const float* __restrict__ Wq,
                                                 const float* __restrict__ Wk,
                                                 const float* __restrict__ Wv,
                                                 half_t* __restrict__ WT) {
    const int k0 = blockIdx.x * 64;
    const int h  = blockIdx.y, z = blockIdx.z;
    const float* W = ((z == 0) ? Wq : (z == 1) ? Wk : Wv) + (size_t)h * FDIM * HD;
    __shared__ float Ls[64][65];
    const int tid = threadIdx.x;
    {
        const int kk = tid >> 2, dg = (tid & 3) * 16;
        #pragma unroll
        for (int j = 0; j < 4; ++j) {
            const float4 w = *(const float4*)(W + (size_t)(k0 + kk) * HD + dg + j * 4);
            Ls[kk][dg + j * 4 + 0] = w.x; Ls[kk][dg + j * 4 + 1] = w.y;
            Ls[kk][dg + j * 4 + 2] = w.z; Ls[kk][dg + j * 4 + 3] = w.w;
        }
    }
    __syncthreads();
    {
        const int d = tid >> 2, kg = (tid & 3) * 16;
        half8v t0, t1;
        #pragma unroll
        for (int j = 0; j < 8; ++j) t0[j] = (half_t)Ls[kg + j][d];
        #pragma unroll
        for (int j = 0; j < 8; ++j) t1[j] = (half_t)Ls[kg + 8 + j][d];
        half_t* dst = WT + ((size_t)(z * NH + h) * HD + d) * FDIM + k0 + kg;
        *(half8v*)dst = t0;
        *(half8v*)(dst + 8) = t1;
    }
}

// ---------------- Kernel 3: QKV projections, LDS-free MFMA, pipelined k-loop ----------------
__global__ __launch_bounds__(256) void qkv_kernel(const half_t* __restrict__ xh,
                                                  const half_t* __restrict__ WT,
                                                  half_t* __restrict__ Qo,
                                                  half_t* __restrict__ Ko,
                                                  half_t* __restrict__ VTo) {
    const int ms0 = blockIdx.x * 64;
    const int h   = blockIdx.y, z = blockIdx.z;
    const half_t* Wt = WT + (size_t)(z * NH + h) * HD * FDIM;   // [64][512] = W^T

    const int tid = threadIdx.x;
    const int wv = tid >> 6, lane = tid & 63;
    const int lo = lane & 15, qq = lane >> 4;

    float4v acc[4];
    #pragma unroll
    for (int cg = 0; cg < 4; ++cg) acc[cg] = (float4v){0.f, 0.f, 0.f, 0.f};

    const half_t* arow = xh + (size_t)(ms0 + wv * 16 + lo) * FDIM + qq * 8;
    half8v a_c = *(const half8v*)(arow);
    half8v b_c[4];
    #pragma unroll
    for (int cg = 0; cg < 4; ++cg)
        b_c[cg] = *(const half8v*)(Wt + (size_t)(cg * 16 + lo) * FDIM + qq * 8);

    for (int k0 = 0; k0 < FDIM; k0 += 32) {
        const int kn = (k0 + 32 < FDIM) ? k0 + 32 : k0;   // clamped redundant prefetch at tail
        half8v a_n = *(const half8v*)(arow + kn);
        half8v b_n[4];
        #pragma unroll
        for (int cg = 0; cg < 4; ++cg)
            b_n[cg] = *(const half8v*)(Wt + (size_t)(cg * 16 + lo) * FDIM + kn + qq * 8);
        #pragma unroll
        for (int cg = 0; cg < 4; ++cg) acc[cg] = MFMA16(a_c, b_c[cg], acc[cg]);
        a_c = a_n;
        #pragma unroll
        for (int cg = 0; cg < 4; ++cg) b_c[cg] = b_n[cg];
    }

    __shared__ float Ls[64][65];
    if (z < 2) {
        half_t* Co = ((z == 0) ? Qo : Ko) + (size_t)h * S_LEN * HD;
        #pragma unroll
        for (int cg = 0; cg < 4; ++cg)
            #pragma unroll
            for (int r = 0; r < 4; ++r)
                Co[(size_t)(ms0 + wv * 16 + qq * 4 + r) * HD + cg * 16 + lo] = (half_t)acc[cg][r];
    } else {
        #pragma unroll
        for (int cg = 0; cg < 4; ++cg)
            #pragma unroll
            for (int r = 0; r < 4; ++r)
                Ls[wv * 16 + qq * 4 + r][cg * 16 + lo] = acc[cg][r];
        __syncthreads();
        const int d = tid & 63, sg = tid >> 6;
        half8v t0, t1;
        #pragma unroll
        for (int j = 0; j < 8; ++j) t0[j] = (half_t)Ls[sg * 16 + j][d];
        #pragma unroll
        for (int j = 0; j < 8; ++j) t1[j] = (half_t)Ls[sg * 16 + 8 + j][d];
        half_t* dst = VTo + (size_t)(h * HD + d) * S_LEN + ms0 + sg * 16;
        *(half8v*)dst = t0;
        *(half8v*)(dst + 8) = t1;
    }
}

// ---------------- Kernel 4: softmax denominators (no-max) -> 1/l, pipelined ----------------
__global__ __launch_bounds__(256) void lsum_kernel(const half_t* __restrict__ Qw,
                                                   const half_t* __restrict__ Kw,
                                                   float* __restrict__ linv) {
    const int s0 = blockIdx.x * 16;
    const int h  = blockIdx.y;
    const half_t* Qh = Qw + (size_t)h * S_LEN * HD;
    const half_t* Kh = Kw + (size_t)h * S_LEN * HD;

    const int tid = threadIdx.x;
    const int wv = tid >> 6, lane = tid & 63;
    const int lo = lane & 15, qq = lane >> 4;

    const half8v aq0 = *(const half8v*)(Qh + (size_t)(s0 + lo) * HD + qq * 8);
    const half8v aq1 = *(const half8v*)(Qh + (size_t)(s0 + lo) * HD + 32 + qq * 8);

    half8v b0c = *(const half8v*)(Kh + (size_t)(wv * 16 + lo) * HD + qq * 8);
    half8v b1c = *(const half8v*)(Kh + (size_t)(wv * 16 + lo) * HD + 32 + qq * 8);

    float esum[4] = {0.f, 0.f, 0.f, 0.f};
    for (int j = 0; j < 32; ++j) {
        const int jn = (j < 31) ? j + 1 : j;
        const int cbn = (wv + 4 * jn) * 16;
        const half8v b0n = *(const half8v*)(Kh + (size_t)(cbn + lo) * HD + qq * 8);
        const half8v b1n = *(const half8v*)(Kh + (size_t)(cbn + lo) * HD + 32 + qq * 8);

        const int cbase = (wv + 4 * j) * 16;
        float4v c4 = {0.f, 0.f, 0.f, 0.f};
        c4 = MFMA16(aq0, b0c, c4);
        c4 = MFMA16(aq1, b1c, c4);
        const int dd0 = cbase - s0;
        const bool near = (dd0 > -24) && (dd0 < 24);
        #pragma unroll
        for (int r = 0; r < 4; ++r) {
            float s = c4[r] * 0.125f;
            if (near) {
                const float d = (float)(s0 + qq * 4 + r - cbase - lo);
                s += __expf(-0.5f * d * d);
            }
            s = fminf(s, 60.f);
            esum[r] += __expf(s);
        }
        b0c = b0n; b1c = b1n;
    }
    #pragma unroll
    for (int r = 0; r < 4; ++r) {
        #pragma unroll
        for (int mk = 1; mk < 16; mk <<= 1) esum[r] += __shfl_xor(esum[r], mk, 64);
    }
    __shared__ float red[4][16];
    if (lo == 0) {
        #pragma unroll
        for (int r = 0; r < 4; ++r) red[wv][qq * 4 + r] = esum[r];
    }
    __syncthreads();
    if (tid < 16) {
        const float l = red[0][tid] + red[1][tid] + red[2][tid] + red[3][tid];
        linv[(size_t)h * S_LEN + s0 + tid] = 1.0f / l;
    }
}

// ---------------- Kernel 5: attention, head-loop software-pipelined ----------------
// grid = (64 q-tiles of 32 rows, 8 col-chunks of 256). 8 waves: rg=wv&1, cq=wv>>1.
// One raw barrier per head (LDS-only waitcnt); Ps double-buffered; next head's
// Q/K fragments prefetched after the barrier so they fly during PV + next QK.
__global__ __launch_bounds__(512, 2) void attn_kernel(const half_t* __restrict__ Qw,
                                                      const half_t* __restrict__ Kw,
                                                      const half_t* __restrict__ VT,
                                                      const float* __restrict__ linv,
                                                      half_t* __restrict__ partial,
                                                      float* __restrict__ out) {
    const int s0 = blockIdx.x * 32;
    const int c0 = blockIdx.y * 256;

    __shared__ half_t Ps[2][32 * PS2];   // 33.8 KB double-buffered

    const int tid = threadIdx.x;
    const int wv = tid >> 6, lane = tid & 63;
    const int rg = wv & 1, cq = wv >> 1;
    const int lo = lane & 15, qq = lane >> 4;
    const int rbase = s0 + rg * 16;

    float msum[4][4];
    #pragma unroll
    for (int ct = 0; ct < 4; ++ct)
        #pragma unroll
        for (int r = 0; r < 4; ++r) msum[ct][r] = 0.f;

    half_t* po = partial + (size_t)blockIdx.y * (size_t)MH_ELEMS;

    // initial (head 0) Q/K fragment loads
    half8v aq0 = *(const half8v*)(Qw + (size_t)(rbase + lo) * HD + qq * 8);
    half8v aq1 = *(const half8v*)(Qw + (size_t)(rbase + lo) * HD + 32 + qq * 8);
    half8v cK[4][2];
    #pragma unroll
    for (int ct = 0; ct < 4; ++ct) {
        const int cb = c0 + cq * 64 + ct * 16;
        cK[ct][0] = *(const half8v*)(Kw + (size_t)(cb + lo) * HD + qq * 8);
        cK[ct][1] = *(const half8v*)(Kw + (size_t)(cb + lo) * HD + 32 + qq * 8);
    }

    for (int h = 0; h < NH; ++h) {
        const half_t* Vt = VT + (size_t)h * (size_t)HD * S_LEN;
        half_t* Psb = Ps[h & 1];

        float li[4];
        #pragma unroll
        for (int r = 0; r < 4; ++r) li[r] = linv[(size_t)h * S_LEN + rbase + qq * 4 + r];

        // ---- V^T fragments for this head's PV: issue early, covered by QK+exp ----
        half8v bv[8];
        #pragma unroll
        for (int ks = 0; ks < 8; ++ks)
            bv[ks] = *(const half8v*)(Vt + (size_t)(cq * 16 + lo) * S_LEN + c0 + ks * 32 + qq * 8);

        // ---- QK -> exp -> msum -> Ps ----
        #pragma unroll
        for (int ct = 0; ct < 4; ++ct) {
            const int cbase = c0 + cq * 64 + ct * 16;
            float4v c4 = {0.f, 0.f, 0.f, 0.f};
            c4 = MFMA16(aq0, cK[ct][0], c4);
            c4 = MFMA16(aq1, cK[ct][1], c4);
            const int dd0 = cbase - rbase;
            const bool near = (dd0 > -24) && (dd0 < 24);
            #pragma unroll
            for (int r = 0; r < 4; ++r) {
                float s = c4[r] * 0.125f;
                if (near) {
                    const float d = (float)(rbase + qq * 4 + r - cbase - lo);
                    s += __expf(-0.5f * d * d);
                }
                s = fminf(s, 60.f);
                const float p = __expf(s) * li[r];
                msum[ct][r] += p;
                Psb[(size_t)(rg * 16 + qq * 4 + r) * PS2 + cq * 64 + ct * 16 + lo] = (half_t)p;
            }
        }

        // raw barrier: drain LDS (Ps writes) only; keep bv/prefetch global loads in flight
        __builtin_amdgcn_s_waitcnt(LDS_ONLY_WAITCNT);
        __builtin_amdgcn_s_barrier();

        // ---- prefetch next head's Q/K fragments (after barrier: not drained) ----
        const int hn = (h < NH - 1) ? h + 1 : h;
        const half_t* Qn = Qw + (size_t)hn * S_LEN * HD;
        const half_t* Kn = Kw + (size_t)hn * S_LEN * HD;
        const half8v nq0 = *(const half8v*)(Qn + (size_t)(rbase + lo) * HD + qq * 8);
        const half8v nq1 = *(const half8v*)(Qn + (size_t)(rbase + lo) * HD + 32 + qq * 8);
        half8v nK[4][2];
        #pragma unroll
        for (int ct = 0; ct < 4; ++ct) {
            const int cb = c0 + cq * 64 + ct * 16;
            nK[ct][0] = *(const half8v*)(Kn + (size_t)(cb + lo) * HD + qq * 8);
            nK[ct][1] = *(const half8v*)(Kn + (size_t)(cb + lo) * HD + 32 + qq * 8);
        }

        // ---- PV ----
        float4v accO = {0.f, 0.f, 0.f, 0.f};
        #pragma unroll
        for (int ks = 0; ks < 8; ++ks) {
            const half8v ap = *(const half8v*)&Psb[(size_t)(rg * 16 + lo) * PS2 + ks * 32 + qq * 8];
            accO = MFMA16(ap, bv[ks], accO);
        }
        #pragma unroll
        for (int r = 0; r < 4; ++r)
            po[(size_t)(rbase + qq * 4 + r) * FDIM + h * HD + cq * 16 + lo] = (half_t)accO[r];

        aq0 = nq0; aq1 = nq1;
        #pragma unroll
        for (int ct = 0; ct < 4; ++ct) { cK[ct][0] = nK[ct][0]; cK[ct][1] = nK[ct][1]; }
    }

    // mean_weights written directly (fp32)
    #pragma unroll
    for (int ct = 0; ct < 4; ++ct)
        #pragma unroll
        for (int r = 0; r < 4; ++r)
            out[MH_ELEMS + (size_t)(rbase + qq * 4 + r) * S_LEN + c0 + cq * 64 + ct * 16 + lo] =
                msum[ct][r] * 0.125f;
}

// ---------------- Kernel 6: reduce 8 f16 chunk-partials -> multi_head_output ----------------
__global__ __launch_bounds__(256) void reduce_kernel(const half_t* __restrict__ partial,
                                                     float* __restrict__ out) {
    const size_t i8 = ((size_t)blockIdx.x * 256 + threadIdx.x) * 8;
    float s[8] = {0.f, 0.f, 0.f, 0.f, 0.f, 0.f, 0.f, 0.f};
    #pragma unroll
    for (int c = 0; c < 8; ++c) {
        const half8v t = *(const half8v*)(partial + (size_t)c * MH_ELEMS + i8);
        #pragma unroll
        for (int j = 0; j < 8; ++j) s[j] += (float)t[j];
    }
    *(float4*)(out + i8)     = make_float4(s[0], s[1], s[2], s[3]);
    *(float4*)(out + i8 + 4) = make_float4(s[4], s[5], s[6], s[7]);
}

extern "C" void kernel_launch(void* const* d_in, const int* in_sizes, int n_in,
                              void* d_out, int out_size, void* d_ws, size_t ws_size,
                              hipStream_t stream) {
    const float* x  = (const float*)d_in[0];
    const float* Wq = (const float*)d_in[1];
    const float* Wk = (const float*)d_in[2];
    const float* Wv = (const float*)d_in[3];
    const float* g  = (const float*)d_in[4];
    const float* b  = (const float*)d_in[5];
    float* out = (float*)d_out;
    char*  ws  = (char*)d_ws;

    half_t* xh   = (half_t*)(ws);                   // 2 MB
    half_t* Qh   = (half_t*)(ws + (2ull  << 20));   // 2 MB
    half_t* Kh   = (half_t*)(ws + (4ull  << 20));   // 2 MB
    half_t* VT   = (half_t*)(ws + (6ull  << 20));   // 2 MB   [8][64][2048]
    half_t* WT   = (half_t*)(ws + (8ull  << 20));   // 1.5 MB [3][8][64][512]
    float*  linv = (float*) (ws + (10ull << 20));   // 64 KB
    half_t* part = (half_t*)(ws + (11ull << 20));   // 16 MB  [8][1M] f16

    ln_pe_kernel<<<S_LEN, 256, 0, stream>>>(x, g, b, xh);
    wt_kernel<<<dim3(8, 8, 3), 256, 0, stream>>>(Wq, Wk, Wv, WT);
    qkv_kernel<<<dim3(32, 8, 3), 256, 0, stream>>>(xh, WT, Qh, Kh, VT);
    lsum_kernel<<<dim3(128, 8), 256, 0, stream>>>(Qh, Kh, linv);
    attn_kernel<<<dim3(64, 8), 512, 0, stream>>>(Qh, Kh, VT, linv, part, out);
    reduce_kernel<<<MH_ELEMS / 8 / 256, 256, 0, stream>>>(part, out);
}

// Round 7
// 205.440 us; speedup vs baseline: 1.0143x; 1.0004x over previous
//
#include <hip/hip_runtime.h>
#include <hip/hip_bf16.h>
#include <math.h>

#define S_LEN 2048
#define FDIM  512
#define NH    8
#define HD    64
#define MH_ELEMS (S_LEN * FDIM)          // 1048576
#define MEAN_ELEMS (S_LEN * S_LEN)       // 4194304

typedef _Float16 half_t;
typedef _Float16 half2v __attribute__((ext_vector_type(2)));
typedef _Float16 half8v __attribute__((ext_vector_type(8)));
typedef float    float4v __attribute__((ext_vector_type(4)));
typedef int      int4v   __attribute__((ext_vector_type(4)));

#define MFMA16(a, b, c) __builtin_amdgcn_mfma_f32_16x16x32_f16((a), (b), (c), 0, 0, 0)

// ---------------- Kernel 1: LayerNorm + PE row 0 -> f16 ----------------
__global__ __launch_bounds__(256) void ln_pe_kernel(const float* __restrict__ x,
                                                    const float* __restrict__ gamma,
                                                    const float* __restrict__ beta,
                                                    half_t* __restrict__ xo) {
    const int row = blockIdx.x;
    const int tid = threadIdx.x;
    const float2 v = ((const float2*)(x + (size_t)row * FDIM))[tid];
    float s = v.x + v.y;
    float q = v.x * v.x + v.y * v.y;
    #pragma unroll
    for (int off = 1; off < 64; off <<= 1) {
        s += __shfl_xor(s, off, 64);
        q += __shfl_xor(q, off, 64);
    }
    __shared__ float red[8];
    const int wave = tid >> 6;
    if ((tid & 63) == 0) { red[wave] = s; red[4 + wave] = q; }
    __syncthreads();
    s = red[0] + red[1] + red[2] + red[3];
    q = red[4] + red[5] + red[6] + red[7];
    const float mu  = s * (1.0f / FDIM);
    const float var = q * (1.0f / FDIM) - mu * mu;
    const float rstd = rsqrtf(var + 1e-5f);
    const int f0 = tid * 2, f1 = tid * 2 + 1;
    const float o0 = (v.x - mu) * rstd * gamma[f0] + beta[f0];
    const float o1 = (v.y - mu) * rstd * gamma[f1] + beta[f1] + 1.0f;
    half2v o; o.x = (half_t)o0; o.y = (half_t)o1;
    ((half2v*)(xo + (size_t)row * FDIM))[tid] = o;
}

// ---------------- Kernel 2: W -> W^T f16  (WT[z][h][d][k]) ----------------
__global__ __launch_bounds__(256) void wt_kernel(const float* __restrict__ Wq,
                                                 const float* __restrict__ Wk,
                                                 const float* __restrict__ Wv,
                                                 half_t* __restrict__ WT) {
    const int k0 = blockIdx.x * 64;
    const int h  = blockIdx.y, z = blockIdx.z;
    const float* W = ((z == 0) ? Wq : (z == 1) ? Wk : Wv) + (size_t)h * FDIM * HD;
    __shared__ float Ls[64][65];
    const int tid = threadIdx.x;
    {
        const int kk = tid >> 2, dg = (tid & 3) * 16;
        #pragma unroll
        for (int j = 0; j < 4; ++j) {
            const float4 w = *(const float4*)(W + (size_t)(k0 + kk) * HD + dg + j * 4);
            Ls[kk][dg + j * 4 + 0] = w.x; Ls[kk][dg + j * 4 + 1] = w.y;
            Ls[kk][dg + j * 4 + 2] = w.z; Ls[kk][dg + j * 4 + 3] = w.w;
        }
    }
    __syncthreads();
    {
        const int d = tid >> 2, kg = (tid & 3) * 16;
        half8v t0, t1;
        #pragma unroll
        for (int j = 0; j < 8; ++j) t0[j] = (half_t)Ls[kg + j][d];
        #pragma unroll
        for (int j = 0; j < 8; ++j) t1[j] = (half_t)Ls[kg + 8 + j][d];
        half_t* dst = WT + ((size_t)(z * NH + h) * HD + d) * FDIM + k0 + kg;
        *(half8v*)dst = t0;
        *(half8v*)(dst + 8) = t1;
    }
}

// ---------------- Kernel 3: QKV projections, LDS-free MFMA, depth-2 pipeline ----------------
__global__ __launch_bounds__(256) void qkv_kernel(const half_t* __restrict__ xh,
                                                  const half_t* __restrict__ WT,
                                                  half_t* __restrict__ Qo,
                                                  half_t* __restrict__ Ko,
                                                  half_t* __restrict__ VTo) {
    const int ms0 = blockIdx.x * 64;
    const int h   = blockIdx.y, z = blockIdx.z;
    const half_t* Wt = WT + (size_t)(z * NH + h) * HD * FDIM;   // [64][512] = W^T

    const int tid = threadIdx.x;
    const int wv = tid >> 6, lane = tid & 63;
    const int lo = lane & 15, qq = lane >> 4;

    float4v acc[4];
    #pragma unroll
    for (int cg = 0; cg < 4; ++cg) acc[cg] = (float4v){0.f, 0.f, 0.f, 0.f};

    const half_t* arow = xh + (size_t)(ms0 + wv * 16 + lo) * FDIM + qq * 8;
    const half_t* wrow[4];
    #pragma unroll
    for (int cg = 0; cg < 4; ++cg) wrow[cg] = Wt + (size_t)(cg * 16 + lo) * FDIM + qq * 8;

    half8v a0 = *(const half8v*)(arow), a1 = *(const half8v*)(arow + 32);
    half8v b0[4], b1[4];
    #pragma unroll
    for (int cg = 0; cg < 4; ++cg) { b0[cg] = *(const half8v*)(wrow[cg]); b1[cg] = *(const half8v*)(wrow[cg] + 32); }

    for (int k0 = 0; k0 < FDIM; k0 += 64) {
        const int kn0 = (k0 + 64 < FDIM) ? k0 + 64 : 0;
        const int kn1 = (k0 + 96 < FDIM) ? k0 + 96 : 0;
        half8v an0 = *(const half8v*)(arow + kn0);
        half8v bn0[4];
        #pragma unroll
        for (int cg = 0; cg < 4; ++cg) bn0[cg] = *(const half8v*)(wrow[cg] + kn0);
        #pragma unroll
        for (int cg = 0; cg < 4; ++cg) acc[cg] = MFMA16(a0, b0[cg], acc[cg]);
        half8v an1 = *(const half8v*)(arow + kn1);
        half8v bn1[4];
        #pragma unroll
        for (int cg = 0; cg < 4; ++cg) bn1[cg] = *(const half8v*)(wrow[cg] + kn1);
        #pragma unroll
        for (int cg = 0; cg < 4; ++cg) acc[cg] = MFMA16(a1, b1[cg], acc[cg]);
        a0 = an0; a1 = an1;
        #pragma unroll
        for (int cg = 0; cg < 4; ++cg) { b0[cg] = bn0[cg]; b1[cg] = bn1[cg]; }
    }

    __shared__ float Ls[64][65];
    if (z < 2) {
        half_t* Co = ((z == 0) ? Qo : Ko) + (size_t)h * S_LEN * HD;
        #pragma unroll
        for (int cg = 0; cg < 4; ++cg)
            #pragma unroll
            for (int r = 0; r < 4; ++r)
                Co[(size_t)(ms0 + wv * 16 + qq * 4 + r) * HD + cg * 16 + lo] = (half_t)acc[cg][r];
    } else {
        #pragma unroll
        for (int cg = 0; cg < 4; ++cg)
            #pragma unroll
            for (int r = 0; r < 4; ++r)
                Ls[wv * 16 + qq * 4 + r][cg * 16 + lo] = acc[cg][r];
        __syncthreads();
        const int d = tid & 63, sg = tid >> 6;
        half8v t0, t1;
        #pragma unroll
        for (int j = 0; j < 8; ++j) t0[j] = (half_t)Ls[sg * 16 + j][d];
        #pragma unroll
        for (int j = 0; j < 8; ++j) t1[j] = (half_t)Ls[sg * 16 + 8 + j][d];
        half_t* dst = VTo + (size_t)(h * HD + d) * S_LEN + ms0 + sg * 16;
        *(half8v*)dst = t0;
        *(half8v*)(dst + 8) = t1;
    }
}

// ---------------- Kernel 4: attention core — one head per block, online max ----------------
// grid = (128 q-tiles of 16 rows, 8 heads), 256 thr = 4 waves, each a 512-col strip.
// S^T = K·Q^T (C: col=q=lo, row=t). Online per-q max (lane-uniform rescale of accO).
// P^T (=e^{s-m} <= 1, f16-safe) built in-registers via shuffles. O^T = V^T·P^T.
// ONE barrier total. Writes out[MH] + linv (= e^{-M}/L for mean_kernel).
__global__ __launch_bounds__(256) void attn2_kernel(const half_t* __restrict__ Qw,
                                                    const half_t* __restrict__ Kw,
                                                    const half_t* __restrict__ VT,
                                                    float* __restrict__ linv_g,
                                                    float* __restrict__ out) {
    const int s0 = blockIdx.x * 16;
    const int h  = blockIdx.y;
    const half_t* Qh = Qw + (size_t)h * S_LEN * HD;
    const half_t* Kh = Kw + (size_t)h * S_LEN * HD;
    const half_t* Vt = VT + (size_t)h * (size_t)HD * S_LEN;

    __shared__ float Osh[4][16][65];
    __shared__ float lsh[4][16];
    __shared__ float msh[4][16];

    const int tid = threadIdx.x;
    const int wv = tid >> 6, lane = tid & 63;
    const int lo = lane & 15, qq = lane >> 4;
    const int tb = wv * 512;

    // Q as B-operand: B[n=lo=q][k=d]
    const half8v q0 = *(const half8v*)(Qh + (size_t)(s0 + lo) * HD + qq * 8);
    const half8v q1 = *(const half8v*)(Qh + (size_t)(s0 + lo) * HD + 32 + qq * 8);

    float4v accO[4];
    #pragma unroll
    for (int dt = 0; dt < 4; ++dt) accO[dt] = (float4v){0.f, 0.f, 0.f, 0.f};
    float m = 0.f;      // running max for q = s0+lo (uniform across qq after reductions)
    float lsum = 0.f;   // this lane's partial sum of e^{s-m} over its t-subset

    const int srcLow  = lo + ((qq & 1) * 2) * 16;
    const int srcHigh = srcLow + 16;
    const bool sel1 = (qq >> 1) != 0;

    // prefetch step 0: K A-frags (2 tiles x 2 k-halves) + V^T A-frags (4 d-tiles)
    half8v kc[4], vc[4];
    {
        const half_t* kp0 = Kh + (size_t)(tb + lo) * HD;
        const half_t* kp1 = Kh + (size_t)(tb + 16 + lo) * HD;
        kc[0] = *(const half8v*)(kp0 + qq * 8);
        kc[1] = *(const half8v*)(kp0 + 32 + qq * 8);
        kc[2] = *(const half8v*)(kp1 + qq * 8);
        kc[3] = *(const half8v*)(kp1 + 32 + qq * 8);
        #pragma unroll
        for (int dt = 0; dt < 4; ++dt)
            vc[dt] = *(const half8v*)(Vt + (size_t)(dt * 16 + lo) * S_LEN + tb + qq * 8);
    }

    for (int ps = 0; ps < 16; ++ps) {
        const int Tg  = tb + ps * 32;
        const int Tgn = tb + ((ps < 15) ? ps + 1 : ps) * 32;
        // prefetch next step
        half8v kn[4], vn[4];
        {
            const half_t* kp0 = Kh + (size_t)(Tgn + lo) * HD;
            const half_t* kp1 = Kh + (size_t)(Tgn + 16 + lo) * HD;
            kn[0] = *(const half8v*)(kp0 + qq * 8);
            kn[1] = *(const half8v*)(kp0 + 32 + qq * 8);
            kn[2] = *(const half8v*)(kp1 + qq * 8);
            kn[3] = *(const half8v*)(kp1 + 32 + qq * 8);
            #pragma unroll
            for (int dt = 0; dt < 4; ++dt)
                vn[dt] = *(const half8v*)(Vt + (size_t)(dt * 16 + lo) * S_LEN + Tgn + qq * 8);
        }
        // S^T tiles: tile0 rows t=Tg+0..15, tile1 rows t=Tg+16..31
        float4v c0 = (float4v){0.f, 0.f, 0.f, 0.f};
        c0 = MFMA16(kc[0], q0, c0);
        c0 = MFMA16(kc[1], q1, c0);
        float4v c1 = (float4v){0.f, 0.f, 0.f, 0.f};
        c1 = MFMA16(kc[2], q0, c1);
        c1 = MFMA16(kc[3], q1, c1);

        float S0[4], S1[4];
        const int dd0 = s0 - Tg;
        const bool near0 = (dd0 > -40) && (dd0 < 40);
        const bool near1 = (dd0 - 16 > -40) && (dd0 - 16 < 40);
        #pragma unroll
        for (int r = 0; r < 4; ++r) {
            float s = c0[r] * 0.125f;
            if (near0) {
                const float d = (float)(s0 + lo - (Tg + qq * 4 + r));
                s += __expf(-0.5f * d * d);
            }
            S0[r] = s;
            float t = c1[r] * 0.125f;
            if (near1) {
                const float d = (float)(s0 + lo - (Tg + 16 + qq * 4 + r));
                t += __expf(-0.5f * d * d);
            }
            S1[r] = t;
        }
        // ---- online max update (per q; uniform across the 4 qq-lanes of each lo) ----
        float smax = fmaxf(fmaxf(fmaxf(S0[0], S0[1]), fmaxf(S0[2], S0[3])),
                           fmaxf(fmaxf(S1[0], S1[1]), fmaxf(S1[2], S1[3])));
        smax = fmaxf(smax, __shfl_xor(smax, 16, 64));
        smax = fmaxf(smax, __shfl_xor(smax, 32, 64));
        const float mn = fmaxf(m, smax);
        const float alpha = __expf(m - mn);
        m = mn;
        float E0[4], E1[4];
        float ls = 0.f;
        #pragma unroll
        for (int r = 0; r < 4; ++r) {
            E0[r] = __expf(S0[r] - mn);
            E1[r] = __expf(S1[r] - mn);
            ls += E0[r] + E1[r];
        }
        lsum = lsum * alpha + ls;
        #pragma unroll
        for (int dt = 0; dt < 4; ++dt)
            #pragma unroll
            for (int i = 0; i < 4; ++i) accO[dt][i] *= alpha;

        // pack E (<=1, f16-safe) and shuffle-build P^T B-frag
        int pk0, pk1, pk2, pk3;
        {
            half2v p;
            p.x = (half_t)E0[0]; p.y = (half_t)E0[1];
            pk0 = __builtin_bit_cast(int, p);
            p.x = (half_t)E0[2]; p.y = (half_t)E0[3];
            pk1 = __builtin_bit_cast(int, p);
            p.x = (half_t)E1[0]; p.y = (half_t)E1[1];
            pk2 = __builtin_bit_cast(int, p);
            p.x = (half_t)E1[2]; p.y = (half_t)E1[3];
            pk3 = __builtin_bit_cast(int, p);
        }
        int4v bi;
        {
            const int l0a = __shfl(pk0, srcLow, 64),  l0b = __shfl(pk2, srcLow, 64);
            const int l1a = __shfl(pk1, srcLow, 64),  l1b = __shfl(pk3, srcLow, 64);
            const int h0a = __shfl(pk0, srcHigh, 64), h0b = __shfl(pk2, srcHigh, 64);
            const int h1a = __shfl(pk1, srcHigh, 64), h1b = __shfl(pk3, srcHigh, 64);
            bi[0] = sel1 ? l0b : l0a;
            bi[1] = sel1 ? l1b : l1a;
            bi[2] = sel1 ? h0b : h0a;
            bi[3] = sel1 ? h1b : h1a;
        }
        const half8v bp = __builtin_bit_cast(half8v, bi);
        #pragma unroll
        for (int dt = 0; dt < 4; ++dt) accO[dt] = MFMA16(vc[dt], bp, accO[dt]);

        #pragma unroll
        for (int i = 0; i < 4; ++i) { kc[i] = kn[i]; vc[i] = vn[i]; }
    }

    // reduce lsum over the 4 qq-groups (m already uniform per lo)
    lsum += __shfl_xor(lsum, 16, 64);
    lsum += __shfl_xor(lsum, 32, 64);
    if (qq == 0) { lsh[wv][lo] = lsum; msh[wv][lo] = m; }
    #pragma unroll
    for (int dt = 0; dt < 4; ++dt)
        #pragma unroll
        for (int r = 0; r < 4; ++r)
            Osh[wv][lo][dt * 16 + qq * 4 + r] = accO[dt][r];
    __syncthreads();

    // cross-wave merge with per-wave max frames. thread -> (q = tid>>4, dg = tid&15)
    {
        const int q = tid >> 4, dg = tid & 15;
        const float m0 = msh[0][q], m1 = msh[1][q], m2 = msh[2][q], m3 = msh[3][q];
        const float M = fmaxf(fmaxf(m0, m1), fmaxf(m2, m3));
        const float f0 = __expf(m0 - M), f1 = __expf(m1 - M);
        const float f2 = __expf(m2 - M), f3 = __expf(m3 - M);
        const float L = lsh[0][q] * f0 + lsh[1][q] * f1 + lsh[2][q] * f2 + lsh[3][q] * f3;
        const float sc = 1.0f / L;
        float4 o;
        o.x = (Osh[0][q][dg * 4 + 0] * f0 + Osh[1][q][dg * 4 + 0] * f1 +
               Osh[2][q][dg * 4 + 0] * f2 + Osh[3][q][dg * 4 + 0] * f3) * sc;
        o.y = (Osh[0][q][dg * 4 + 1] * f0 + Osh[1][q][dg * 4 + 1] * f1 +
               Osh[2][q][dg * 4 + 1] * f2 + Osh[3][q][dg * 4 + 1] * f3) * sc;
        o.z = (Osh[0][q][dg * 4 + 2] * f0 + Osh[1][q][dg * 4 + 2] * f1 +
               Osh[2][q][dg * 4 + 2] * f2 + Osh[3][q][dg * 4 + 2] * f3) * sc;
        o.w = (Osh[0][q][dg * 4 + 3] * f0 + Osh[1][q][dg * 4 + 3] * f1 +
               Osh[2][q][dg * 4 + 3] * f2 + Osh[3][q][dg * 4 + 3] * f3) * sc;
        *(float4*)(out + (size_t)(s0 + q) * FDIM + h * HD + dg * 4) = o;
        if (tid < 16) {
            const float n0 = msh[0][tid], n1 = msh[1][tid], n2 = msh[2][tid], n3 = msh[3][tid];
            const float M2 = fmaxf(fmaxf(n0, n1), fmaxf(n2, n3));
            const float L2 = lsh[0][tid] * __expf(n0 - M2) + lsh[1][tid] * __expf(n1 - M2) +
                             lsh[2][tid] * __expf(n2 - M2) + lsh[3][tid] * __expf(n3 - M2);
            // linv = e^{-M}/L so that p = e^{s} * linv = e^{s-M}/L (fp32-safe)
            linv_g[(size_t)h * S_LEN + s0 + tid] = __expf(-M2) / L2;
        }
    }
}

// ---------------- Kernel 5: mean_weights — QK recompute, barrier-free ----------------
// grid = (64 q-tiles of 32 rows, 8 col-chunks of 256). 8 waves: rg=wv&1, cq=wv>>1.
__global__ __launch_bounds__(512) void mean_kernel(const half_t* __restrict__ Qw,
                                                   const half_t* __restrict__ Kw,
                                                   const float* __restrict__ linv,
                                                   float* __restrict__ out) {
    const int s0 = blockIdx.x * 32;
    const int c0 = blockIdx.y * 256;

    const int tid = threadIdx.x;
    const int wv = tid >> 6, lane = tid & 63;
    const int rg = wv & 1, cq = wv >> 1;
    const int lo = lane & 15, qq = lane >> 4;
    const int rbase = s0 + rg * 16;

    float msum[4][4];
    #pragma unroll
    for (int ct = 0; ct < 4; ++ct)
        #pragma unroll
        for (int r = 0; r < 4; ++r) msum[ct][r] = 0.f;

    half8v aq0 = *(const half8v*)(Qw + (size_t)(rbase + lo) * HD + qq * 8);
    half8v aq1 = *(const half8v*)(Qw + (size_t)(rbase + lo) * HD + 32 + qq * 8);
    half8v cK[4][2];
    #pragma unroll
    for (int ct = 0; ct < 4; ++ct) {
        const int cb = c0 + cq * 64 + ct * 16;
        cK[ct][0] = *(const half8v*)(Kw + (size_t)(cb + lo) * HD + qq * 8);
        cK[ct][1] = *(const half8v*)(Kw + (size_t)(cb + lo) * HD + 32 + qq * 8);
    }

    for (int h = 0; h < NH; ++h) {
        float li[4];
        #pragma unroll
        for (int r = 0; r < 4; ++r) li[r] = linv[(size_t)h * S_LEN + rbase + qq * 4 + r];

        // prefetch next head's fragments
        const int hn = (h < NH - 1) ? h + 1 : h;
        const half_t* Qn = Qw + (size_t)hn * S_LEN * HD;
        const half_t* Kn = Kw + (size_t)hn * S_LEN * HD;
        const half8v nq0 = *(const half8v*)(Qn + (size_t)(rbase + lo) * HD + qq * 8);
        const half8v nq1 = *(const half8v*)(Qn + (size_t)(rbase + lo) * HD + 32 + qq * 8);
        half8v nK[4][2];
        #pragma unroll
        for (int ct = 0; ct < 4; ++ct) {
            const int cb = c0 + cq * 64 + ct * 16;
            nK[ct][0] = *(const half8v*)(Kn + (size_t)(cb + lo) * HD + qq * 8);
            nK[ct][1] = *(const half8v*)(Kn + (size_t)(cb + lo) * HD + 32 + qq * 8);
        }

        #pragma unroll
        for (int ct = 0; ct < 4; ++ct) {
            const int cbase = c0 + cq * 64 + ct * 16;
            float4v c4 = (float4v){0.f, 0.f, 0.f, 0.f};
            c4 = MFMA16(aq0, cK[ct][0], c4);
            c4 = MFMA16(aq1, cK[ct][1], c4);
            const int dd0 = cbase - rbase;
            const bool near = (dd0 > -40) && (dd0 < 40);
            #pragma unroll
            for (int r = 0; r < 4; ++r) {
                float s = c4[r] * 0.125f;
                if (near) {
                    const float d = (float)(rbase + qq * 4 + r - cbase - lo);
                    s += __expf(-0.5f * d * d);
                }
                msum[ct][r] += __expf(fminf(s, 80.f)) * li[r];
            }
        }
        aq0 = nq0; aq1 = nq1;
        #pragma unroll
        for (int ct = 0; ct < 4; ++ct) { cK[ct][0] = nK[ct][0]; cK[ct][1] = nK[ct][1]; }
    }

    #pragma unroll
    for (int ct = 0; ct < 4; ++ct)
        #pragma unroll
        for (int r = 0; r < 4; ++r)
            out[MH_ELEMS + (size_t)(rbase + qq * 4 + r) * S_LEN + c0 + cq * 64 + ct * 16 + lo] =
                msum[ct][r] * 0.125f;
}

extern "C" void kernel_launch(void* const* d_in, const int* in_sizes, int n_in,
                              void* d_out, int out_size, void* d_ws, size_t ws_size,
                              hipStream_t stream) {
    const float* x  = (const float*)d_in[0];
    const float* Wq = (const float*)d_in[1];
    const float* Wk = (const float*)d_in[2];
    const float* Wv = (const float*)d_in[3];
    const float* g  = (const float*)d_in[4];
    const float* b  = (const float*)d_in[5];
    float* out = (float*)d_out;
    char*  ws  = (char*)d_ws;

    half_t* xh   = (half_t*)(ws);                   // 2 MB
    half_t* Qh   = (half_t*)(ws + (2ull  << 20));   // 2 MB
    half_t* Kh   = (half_t*)(ws + (4ull  << 20));   // 2 MB
    half_t* VT   = (half_t*)(ws + (6ull  << 20));   // 2 MB   [8][64][2048]
    half_t* WT   = (half_t*)(ws + (8ull  << 20));   // 1.5 MB [3][8][64][512]
    float*  linv = (float*) (ws + (10ull << 20));   // 64 KB  [8][2048]

    ln_pe_kernel<<<S_LEN, 256, 0, stream>>>(x, g, b, xh);
    wt_kernel<<<dim3(8, 8, 3), 256, 0, stream>>>(Wq, Wk, Wv, WT);
    qkv_kernel<<<dim3(32, 8, 3), 256, 0, stream>>>(xh, WT, Qh, Kh, VT);
    attn2_kernel<<<dim3(128, 8), 256, 0, stream>>>(Qh, Kh, VT, linv, out);
    mean_kernel<<<dim3(64, 8), 512, 0, stream>>>(Qh, Kh, linv, out);
}

// Round 8
// 185.126 us; speedup vs baseline: 1.1256x; 1.1097x over previous
//
#include <hip/hip_runtime.h>
#include <hip/hip_bf16.h>
#include <math.h>

#define S_LEN 2048
#define FDIM  512
#define NH    8
#define HD    64
#define MH_ELEMS (S_LEN * FDIM)          // 1048576
#define MEAN_ELEMS (S_LEN * S_LEN)       // 4194304

typedef _Float16 half_t;
typedef _Float16 half2v __attribute__((ext_vector_type(2)));
typedef _Float16 half4v __attribute__((ext_vector_type(4)));
typedef _Float16 half8v __attribute__((ext_vector_type(8)));
typedef float    float4v __attribute__((ext_vector_type(4)));
typedef int      int4v   __attribute__((ext_vector_type(4)));
typedef unsigned short ushort4v __attribute__((ext_vector_type(4)));

#define MFMA16(a, b, c) __builtin_amdgcn_mfma_f32_16x16x32_f16((a), (b), (c), 0, 0, 0)

static __device__ __forceinline__ unsigned short f2bf(float x) {
    union { __hip_bfloat16 b; unsigned short u; } cv;
    cv.b = __float2bfloat16(x);
    return cv.u;
}

// ---------------- Kernel 1: LayerNorm + PE row 0 -> f16 ----------------
__global__ __launch_bounds__(256) void ln_pe_kernel(const float* __restrict__ x,
                                                    const float* __restrict__ gamma,
                                                    const float* __restrict__ beta,
                                                    half_t* __restrict__ xo) {
    const int row = blockIdx.x;
    const int tid = threadIdx.x;
    const float2 v = ((const float2*)(x + (size_t)row * FDIM))[tid];
    float s = v.x + v.y;
    float q = v.x * v.x + v.y * v.y;
    #pragma unroll
    for (int off = 1; off < 64; off <<= 1) {
        s += __shfl_xor(s, off, 64);
        q += __shfl_xor(q, off, 64);
    }
    __shared__ float red[8];
    const int wave = tid >> 6;
    if ((tid & 63) == 0) { red[wave] = s; red[4 + wave] = q; }
    __syncthreads();
    s = red[0] + red[1] + red[2] + red[3];
    q = red[4] + red[5] + red[6] + red[7];
    const float mu  = s * (1.0f / FDIM);
    const float var = q * (1.0f / FDIM) - mu * mu;
    const float rstd = rsqrtf(var + 1e-5f);
    const int f0 = tid * 2, f1 = tid * 2 + 1;
    const float o0 = (v.x - mu) * rstd * gamma[f0] + beta[f0];
    const float o1 = (v.y - mu) * rstd * gamma[f1] + beta[f1] + 1.0f;
    half2v o; o.x = (half_t)o0; o.y = (half_t)o1;
    ((half2v*)(xo + (size_t)row * FDIM))[tid] = o;
}

// ---------------- Kernel 2: W -> W^T f16  (WT[z][h][d][k]) ----------------
__global__ __launch_bounds__(256) void wt_kernel(const float* __restrict__ Wq,
                                                 const float* __restrict__ Wk,
                                                 const float* __restrict__ Wv,
                                                 half_t* __restrict__ WT) {
    const int k0 = blockIdx.x * 64;
    const int h  = blockIdx.y, z = blockIdx.z;
    const float* W = ((z == 0) ? Wq : (z == 1) ? Wk : Wv) + (size_t)h * FDIM * HD;
    __shared__ float Ls[64][65];
    const int tid = threadIdx.x;
    {
        const int kk = tid >> 2, dg = (tid & 3) * 16;
        #pragma unroll
        for (int j = 0; j < 4; ++j) {
            const float4 w = *(const float4*)(W + (size_t)(k0 + kk) * HD + dg + j * 4);
            Ls[kk][dg + j * 4 + 0] = w.x; Ls[kk][dg + j * 4 + 1] = w.y;
            Ls[kk][dg + j * 4 + 2] = w.z; Ls[kk][dg + j * 4 + 3] = w.w;
        }
    }
    __syncthreads();
    {
        const int d = tid >> 2, kg = (tid & 3) * 16;
        half8v t0, t1;
        #pragma unroll
        for (int j = 0; j < 8; ++j) t0[j] = (half_t)Ls[kg + j][d];
        #pragma unroll
        for (int j = 0; j < 8; ++j) t1[j] = (half_t)Ls[kg + 8 + j][d];
        half_t* dst = WT + ((size_t)(z * NH + h) * HD + d) * FDIM + k0 + kg;
        *(half8v*)dst = t0;
        *(half8v*)(dst + 8) = t1;
    }
}

// ---------------- Kernel 3: QKV projections, LDS-free MFMA, depth-2 pipeline ----------------
__global__ __launch_bounds__(256) void qkv_kernel(const half_t* __restrict__ xh,
                                                  const half_t* __restrict__ WT,
                                                  half_t* __restrict__ Qo,
                                                  half_t* __restrict__ Ko,
                                                  half_t* __restrict__ VTo) {
    const int ms0 = blockIdx.x * 64;
    const int h   = blockIdx.y, z = blockIdx.z;
    const half_t* Wt = WT + (size_t)(z * NH + h) * HD * FDIM;   // [64][512] = W^T

    const int tid = threadIdx.x;
    const int wv = tid >> 6, lane = tid & 63;
    const int lo = lane & 15, qq = lane >> 4;

    float4v acc[4];
    #pragma unroll
    for (int cg = 0; cg < 4; ++cg) acc[cg] = (float4v){0.f, 0.f, 0.f, 0.f};

    const half_t* arow = xh + (size_t)(ms0 + wv * 16 + lo) * FDIM + qq * 8;
    const half_t* wrow[4];
    #pragma unroll
    for (int cg = 0; cg < 4; ++cg) wrow[cg] = Wt + (size_t)(cg * 16 + lo) * FDIM + qq * 8;

    half8v a0 = *(const half8v*)(arow), a1 = *(const half8v*)(arow + 32);
    half8v b0[4], b1[4];
    #pragma unroll
    for (int cg = 0; cg < 4; ++cg) { b0[cg] = *(const half8v*)(wrow[cg]); b1[cg] = *(const half8v*)(wrow[cg] + 32); }

    for (int k0 = 0; k0 < FDIM; k0 += 64) {
        const int kn0 = (k0 + 64 < FDIM) ? k0 + 64 : 0;
        const int kn1 = (k0 + 96 < FDIM) ? k0 + 96 : 0;
        half8v an0 = *(const half8v*)(arow + kn0);
        half8v bn0[4];
        #pragma unroll
        for (int cg = 0; cg < 4; ++cg) bn0[cg] = *(const half8v*)(wrow[cg] + kn0);
        #pragma unroll
        for (int cg = 0; cg < 4; ++cg) acc[cg] = MFMA16(a0, b0[cg], acc[cg]);
        half8v an1 = *(const half8v*)(arow + kn1);
        half8v bn1[4];
        #pragma unroll
        for (int cg = 0; cg < 4; ++cg) bn1[cg] = *(const half8v*)(wrow[cg] + kn1);
        #pragma unroll
        for (int cg = 0; cg < 4; ++cg) acc[cg] = MFMA16(a1, b1[cg], acc[cg]);
        a0 = an0; a1 = an1;
        #pragma unroll
        for (int cg = 0; cg < 4; ++cg) { b0[cg] = bn0[cg]; b1[cg] = bn1[cg]; }
    }

    __shared__ float Ls[64][65];
    if (z < 2) {
        half_t* Co = ((z == 0) ? Qo : Ko) + (size_t)h * S_LEN * HD;
        #pragma unroll
        for (int cg = 0; cg < 4; ++cg)
            #pragma unroll
            for (int r = 0; r < 4; ++r)
                Co[(size_t)(ms0 + wv * 16 + qq * 4 + r) * HD + cg * 16 + lo] = (half_t)acc[cg][r];
    } else {
        #pragma unroll
        for (int cg = 0; cg < 4; ++cg)
            #pragma unroll
            for (int r = 0; r < 4; ++r)
                Ls[wv * 16 + qq * 4 + r][cg * 16 + lo] = acc[cg][r];
        __syncthreads();
        const int d = tid & 63, sg = tid >> 6;
        half8v t0, t1;
        #pragma unroll
        for (int j = 0; j < 8; ++j) t0[j] = (half_t)Ls[sg * 16 + j][d];
        #pragma unroll
        for (int j = 0; j < 8; ++j) t1[j] = (half_t)Ls[sg * 16 + 8 + j][d];
        half_t* dst = VTo + (size_t)(h * HD + d) * S_LEN + ms0 + sg * 16;
        *(half8v*)dst = t0;
        *(half8v*)(dst + 8) = t1;
    }
}

// ---------------- Kernel 4: attention core — t-split flash blocks + raw-E export ----------------
// grid = (128 q-tiles of 16, 8 heads, 2 t-halves of 1024), 256 thr = 4 waves (256-t strips).
// S^T = K·Q^T; online per-q max; P^T (f16, <=1) built via shuffles; O^T = V^T·P^T.
// Exports raw e^s (bf16) for the mean pass. Writes per-(z,h,q) partial (M, L, O-unnormalized f16).
__global__ __launch_bounds__(256) void attn2_kernel(const half_t* __restrict__ Qw,
                                                    const half_t* __restrict__ Kw,
                                                    const half_t* __restrict__ VT,
                                                    unsigned short* __restrict__ Praw,
                                                    half_t* __restrict__ Op,
                                                    float* __restrict__ mp,
                                                    float* __restrict__ lp) {
    const int s0 = blockIdx.x * 16;
    const int h  = blockIdx.y;
    const int z  = blockIdx.z;
    const half_t* Qh = Qw + (size_t)h * S_LEN * HD;
    const half_t* Kh = Kw + (size_t)h * S_LEN * HD;
    const half_t* Vt = VT + (size_t)h * (size_t)HD * S_LEN;

    __shared__ float Osh[4][16][65];
    __shared__ float lsh[4][16];
    __shared__ float msh[4][16];

    const int tid = threadIdx.x;
    const int wv = tid >> 6, lane = tid & 63;
    const int lo = lane & 15, qq = lane >> 4;
    const int tb = z * 1024 + wv * 256;

    const half8v q0 = *(const half8v*)(Qh + (size_t)(s0 + lo) * HD + qq * 8);
    const half8v q1 = *(const half8v*)(Qh + (size_t)(s0 + lo) * HD + 32 + qq * 8);

    float4v accO[4];
    #pragma unroll
    for (int dt = 0; dt < 4; ++dt) accO[dt] = (float4v){0.f, 0.f, 0.f, 0.f};
    float m = 0.f;
    float lsum = 0.f;

    const int srcLow  = lo + ((qq & 1) * 2) * 16;
    const int srcHigh = srcLow + 16;
    const bool sel1 = (qq >> 1) != 0;

    unsigned short* prb = Praw + ((size_t)h << 22) + (size_t)(s0 + lo) * S_LEN + qq * 4;

    half8v kc[4], vc[4];
    {
        const half_t* kp0 = Kh + (size_t)(tb + lo) * HD;
        const half_t* kp1 = Kh + (size_t)(tb + 16 + lo) * HD;
        kc[0] = *(const half8v*)(kp0 + qq * 8);
        kc[1] = *(const half8v*)(kp0 + 32 + qq * 8);
        kc[2] = *(const half8v*)(kp1 + qq * 8);
        kc[3] = *(const half8v*)(kp1 + 32 + qq * 8);
        #pragma unroll
        for (int dt = 0; dt < 4; ++dt)
            vc[dt] = *(const half8v*)(Vt + (size_t)(dt * 16 + lo) * S_LEN + tb + qq * 8);
    }

    for (int ps = 0; ps < 8; ++ps) {
        const int Tg  = tb + ps * 32;
        const int Tgn = tb + ((ps < 7) ? ps + 1 : ps) * 32;
        half8v kn[4], vn[4];
        {
            const half_t* kp0 = Kh + (size_t)(Tgn + lo) * HD;
            const half_t* kp1 = Kh + (size_t)(Tgn + 16 + lo) * HD;
            kn[0] = *(const half8v*)(kp0 + qq * 8);
            kn[1] = *(const half8v*)(kp0 + 32 + qq * 8);
            kn[2] = *(const half8v*)(kp1 + qq * 8);
            kn[3] = *(const half8v*)(kp1 + 32 + qq * 8);
            #pragma unroll
            for (int dt = 0; dt < 4; ++dt)
                vn[dt] = *(const half8v*)(Vt + (size_t)(dt * 16 + lo) * S_LEN + Tgn + qq * 8);
        }
        float4v c0 = (float4v){0.f, 0.f, 0.f, 0.f};
        c0 = MFMA16(kc[0], q0, c0);
        c0 = MFMA16(kc[1], q1, c0);
        float4v c1 = (float4v){0.f, 0.f, 0.f, 0.f};
        c1 = MFMA16(kc[2], q0, c1);
        c1 = MFMA16(kc[3], q1, c1);

        float S0[4], S1[4];
        const int dd0 = s0 - Tg;
        const bool near0 = (dd0 > -40) && (dd0 < 40);
        const bool near1 = (dd0 - 16 > -40) && (dd0 - 16 < 40);
        #pragma unroll
        for (int r = 0; r < 4; ++r) {
            float s = c0[r] * 0.125f;
            if (near0) {
                const float d = (float)(s0 + lo - (Tg + qq * 4 + r));
                s += __expf(-0.5f * d * d);
            }
            S0[r] = s;
            float t = c1[r] * 0.125f;
            if (near1) {
                const float d = (float)(s0 + lo - (Tg + 16 + qq * 4 + r));
                t += __expf(-0.5f * d * d);
            }
            S1[r] = t;
        }
        float smax = fmaxf(fmaxf(fmaxf(S0[0], S0[1]), fmaxf(S0[2], S0[3])),
                           fmaxf(fmaxf(S1[0], S1[1]), fmaxf(S1[2], S1[3])));
        smax = fmaxf(smax, __shfl_xor(smax, 16, 64));
        smax = fmaxf(smax, __shfl_xor(smax, 32, 64));
        const float mn = fmaxf(m, smax);
        const float alpha = __expf(m - mn);
        m = mn;
        float E0[4], E1[4];
        float ls = 0.f;
        #pragma unroll
        for (int r = 0; r < 4; ++r) {
            E0[r] = __expf(S0[r] - mn);
            E1[r] = __expf(S1[r] - mn);
            ls += E0[r] + E1[r];
        }
        lsum = lsum * alpha + ls;
        #pragma unroll
        for (int dt = 0; dt < 4; ++dt)
            #pragma unroll
            for (int i = 0; i < 4; ++i) accO[dt][i] *= alpha;

        // ---- raw e^s export (bf16, fire-and-forget) ----
        {
            const float emn = __expf(mn);
            ushort4v ep0, ep1;
            #pragma unroll
            for (int r = 0; r < 4; ++r) {
                ep0[r] = f2bf(E0[r] * emn);
                ep1[r] = f2bf(E1[r] * emn);
            }
            unsigned short* pr = prb + Tg;
            *(ushort4v*)pr = ep0;
            *(ushort4v*)(pr + 16) = ep1;
        }

        // pack E (f16-safe) and shuffle-build P^T B-frag
        int pk0, pk1, pk2, pk3;
        {
            half2v p;
            p.x = (half_t)E0[0]; p.y = (half_t)E0[1];
            pk0 = __builtin_bit_cast(int, p);
            p.x = (half_t)E0[2]; p.y = (half_t)E0[3];
            pk1 = __builtin_bit_cast(int, p);
            p.x = (half_t)E1[0]; p.y = (half_t)E1[1];
            pk2 = __builtin_bit_cast(int, p);
            p.x = (half_t)E1[2]; p.y = (half_t)E1[3];
            pk3 = __builtin_bit_cast(int, p);
        }
        int4v bi;
        {
            const int l0a = __shfl(pk0, srcLow, 64),  l0b = __shfl(pk2, srcLow, 64);
            const int l1a = __shfl(pk1, srcLow, 64),  l1b = __shfl(pk3, srcLow, 64);
            const int h0a = __shfl(pk0, srcHigh, 64), h0b = __shfl(pk2, srcHigh, 64);
            const int h1a = __shfl(pk1, srcHigh, 64), h1b = __shfl(pk3, srcHigh, 64);
            bi[0] = sel1 ? l0b : l0a;
            bi[1] = sel1 ? l1b : l1a;
            bi[2] = sel1 ? h0b : h0a;
            bi[3] = sel1 ? h1b : h1a;
        }
        const half8v bp = __builtin_bit_cast(half8v, bi);
        #pragma unroll
        for (int dt = 0; dt < 4; ++dt) accO[dt] = MFMA16(vc[dt], bp, accO[dt]);

        #pragma unroll
        for (int i = 0; i < 4; ++i) { kc[i] = kn[i]; vc[i] = vn[i]; }
    }

    lsum += __shfl_xor(lsum, 16, 64);
    lsum += __shfl_xor(lsum, 32, 64);
    if (qq == 0) { lsh[wv][lo] = lsum; msh[wv][lo] = m; }
    #pragma unroll
    for (int dt = 0; dt < 4; ++dt)
        #pragma unroll
        for (int r = 0; r < 4; ++r)
            Osh[wv][lo][dt * 16 + qq * 4 + r] = accO[dt][r];
    __syncthreads();

    // in-block merge across 4 waves -> UNNORMALIZED partial (M, L, O) for this z-half
    {
        const int q = tid >> 4, dg = tid & 15;
        const float m0 = msh[0][q], m1 = msh[1][q], m2 = msh[2][q], m3 = msh[3][q];
        const float M = fmaxf(fmaxf(m0, m1), fmaxf(m2, m3));
        const float f0 = __expf(m0 - M), f1 = __expf(m1 - M);
        const float f2 = __expf(m2 - M), f3 = __expf(m3 - M);
        const float L = lsh[0][q] * f0 + lsh[1][q] * f1 + lsh[2][q] * f2 + lsh[3][q] * f3;
        half4v o;
        #pragma unroll
        for (int i = 0; i < 4; ++i) {
            const float ov = Osh[0][q][dg * 4 + i] * f0 + Osh[1][q][dg * 4 + i] * f1 +
                             Osh[2][q][dg * 4 + i] * f2 + Osh[3][q][dg * 4 + i] * f3;
            o[i] = (half_t)ov;
        }
        const size_t pidx = (size_t)(z * NH + h) * S_LEN + s0 + q;
        *(half4v*)(Op + pidx * HD + dg * 4) = o;
        if (dg == 0) { mp[pidx] = M; lp[pidx] = L; }
    }
}

// ---------------- Kernel 5: merge the two t-half partials -> out[MH] + linv ----------------
__global__ __launch_bounds__(256) void merge_kernel(const half_t* __restrict__ Op,
                                                    const float* __restrict__ mp,
                                                    const float* __restrict__ lp,
                                                    float* __restrict__ linv,
                                                    float* __restrict__ out) {
    const int s0 = blockIdx.x * 16, h = blockIdx.y;
    const int tid = threadIdx.x, q = tid >> 4, dg = tid & 15;
    const size_t i0 = (size_t)h * S_LEN + s0 + q;
    const size_t i1 = (size_t)(NH + h) * S_LEN + s0 + q;
    const float m0 = mp[i0], m1 = mp[i1], l0 = lp[i0], l1 = lp[i1];
    const float M = fmaxf(m0, m1);
    const float f0 = __expf(m0 - M), f1 = __expf(m1 - M);
    const float L = l0 * f0 + l1 * f1;
    const float inv = 1.0f / L;
    const half4v o0 = *(const half4v*)(Op + i0 * HD + dg * 4);
    const half4v o1 = *(const half4v*)(Op + i1 * HD + dg * 4);
    float4 o;
    o.x = ((float)o0[0] * f0 + (float)o1[0] * f1) * inv;
    o.y = ((float)o0[1] * f0 + (float)o1[1] * f1) * inv;
    o.z = ((float)o0[2] * f0 + (float)o1[2] * f1) * inv;
    o.w = ((float)o0[3] * f0 + (float)o1[3] * f1) * inv;
    *(float4*)(out + (size_t)(s0 + q) * FDIM + h * HD + dg * 4) = o;
    if (dg == 0) linv[(size_t)h * S_LEN + s0 + q] = __expf(-M) * inv;
}

// ---------------- Kernel 6: mean_weights = (1/8) sum_h rawE * linv ----------------
__global__ __launch_bounds__(256) void mean_kernel(const unsigned short* __restrict__ Praw,
                                                   const float* __restrict__ linv,
                                                   float* __restrict__ out) {
    const size_t idx = ((size_t)blockIdx.x * 256 + threadIdx.x) * 8;
    const int q = (int)(idx >> 11);
    float acc[8] = {0.f, 0.f, 0.f, 0.f, 0.f, 0.f, 0.f, 0.f};
    #pragma unroll
    for (int h = 0; h < NH; ++h) {
        const uint4 u = *(const uint4*)(Praw + ((size_t)h << 22) + idx);
        const float li = linv[h * S_LEN + q];
        const unsigned int uu[4] = {u.x, u.y, u.z, u.w};
        #pragma unroll
        for (int j = 0; j < 4; ++j) {
            const float a = __builtin_bit_cast(float, uu[j] << 16);
            const float b = __builtin_bit_cast(float, uu[j] & 0xFFFF0000u);
            acc[2 * j]     += a * li;
            acc[2 * j + 1] += b * li;
        }
    }
    float* o = out + MH_ELEMS + idx;
    *(float4*)o       = make_float4(acc[0] * 0.125f, acc[1] * 0.125f, acc[2] * 0.125f, acc[3] * 0.125f);
    *(float4*)(o + 4) = make_float4(acc[4] * 0.125f, acc[5] * 0.125f, acc[6] * 0.125f, acc[7] * 0.125f);
}

extern "C" void kernel_launch(void* const* d_in, const int* in_sizes, int n_in,
                              void* d_out, int out_size, void* d_ws, size_t ws_size,
                              hipStream_t stream) {
    const float* x  = (const float*)d_in[0];
    const float* Wq = (const float*)d_in[1];
    const float* Wk = (const float*)d_in[2];
    const float* Wv = (const float*)d_in[3];
    const float* g  = (const float*)d_in[4];
    const float* b  = (const float*)d_in[5];
    float* out = (float*)d_out;
    char*  ws  = (char*)d_ws;

    half_t* Qh   = (half_t*)(ws);                            // [0, 2MB)
    half_t* Kh   = (half_t*)(ws + (2ull  << 20));            // [2, 4)
    half_t* VT   = (half_t*)(ws + (4ull  << 20));            // [4, 6)   [8][64][2048] f16
    half_t* xh   = (half_t*)(ws + (6ull  << 20));            // [6, 8)
    half_t* WT   = (half_t*)(ws + (8ull  << 20));            // [8, 9.5) [3][8][64][512] f16
    half_t* Op   = (half_t*)(ws + (10ull << 20));            // [10, 14) [2][8][2048][64] f16
    float*  mp   = (float*) (ws + (14ull << 20));            // 128 KB   [2][8][2048]
    float*  lp   = (float*) (ws + (14ull << 20) + (128ull << 10)); // 128 KB
    float*  linv = (float*) (ws + (14ull << 20) + (512ull << 10)); // 64 KB [8][2048]
    unsigned short* Praw = (unsigned short*)(ws + (16ull << 20));  // [16, 80) [8][2048][2048] bf16

    ln_pe_kernel<<<S_LEN, 256, 0, stream>>>(x, g, b, xh);
    wt_kernel<<<dim3(8, 8, 3), 256, 0, stream>>>(Wq, Wk, Wv, WT);
    qkv_kernel<<<dim3(32, 8, 3), 256, 0, stream>>>(xh, WT, Qh, Kh, VT);
    attn2_kernel<<<dim3(128, 8, 2), 256, 0, stream>>>(Qh, Kh, VT, Praw, Op, mp, lp);
    merge_kernel<<<dim3(128, 8), 256, 0, stream>>>(Op, mp, lp, linv, out);
    mean_kernel<<<MEAN_ELEMS / 8 / 256, 256, 0, stream>>>(Praw, linv, out);
}

// Round 9
// 158.438 us; speedup vs baseline: 1.3153x; 1.1685x over previous
//
#include <hip/hip_runtime.h>
#include <hip/hip_bf16.h>
#include <math.h>

#define S_LEN 2048
#define FDIM  512
#define NH    8
#define HD    64
#define MH_ELEMS (S_LEN * FDIM)          // 1048576
#define MEAN_ELEMS (S_LEN * S_LEN)       // 4194304

typedef _Float16 half_t;
typedef _Float16 half2v __attribute__((ext_vector_type(2)));
typedef _Float16 half4v __attribute__((ext_vector_type(4)));
typedef _Float16 half8v __attribute__((ext_vector_type(8)));
typedef float    float4v __attribute__((ext_vector_type(4)));
typedef int      int4v   __attribute__((ext_vector_type(4)));
typedef unsigned short ushort4v __attribute__((ext_vector_type(4)));

#define MFMA16(a, b, c) __builtin_amdgcn_mfma_f32_16x16x32_f16((a), (b), (c), 0, 0, 0)

static __device__ __forceinline__ unsigned short f2bf(float x) {
    union { __hip_bfloat16 b; unsigned short u; } cv;
    cv.b = __float2bfloat16(x);
    return cv.u;
}

// ---------------- Kernel 1: prep = LayerNorm+PE (blocks 0..2047) | W->W^T f16 (2048..2239) ----------------
__global__ __launch_bounds__(256) void prep_kernel(const float* __restrict__ x,
                                                   const float* __restrict__ gamma,
                                                   const float* __restrict__ beta,
                                                   const float* __restrict__ Wq,
                                                   const float* __restrict__ Wk,
                                                   const float* __restrict__ Wv,
                                                   half_t* __restrict__ xo,
                                                   half_t* __restrict__ WT) {
    const int tid = threadIdx.x;
    if (blockIdx.x < 2048) {
        const int row = blockIdx.x;
        const float2 v = ((const float2*)(x + (size_t)row * FDIM))[tid];
        float s = v.x + v.y;
        float q = v.x * v.x + v.y * v.y;
        #pragma unroll
        for (int off = 1; off < 64; off <<= 1) {
            s += __shfl_xor(s, off, 64);
            q += __shfl_xor(q, off, 64);
        }
        __shared__ float red[8];
        const int wave = tid >> 6;
        if ((tid & 63) == 0) { red[wave] = s; red[4 + wave] = q; }
        __syncthreads();
        s = red[0] + red[1] + red[2] + red[3];
        q = red[4] + red[5] + red[6] + red[7];
        const float mu  = s * (1.0f / FDIM);
        const float var = q * (1.0f / FDIM) - mu * mu;
        const float rstd = rsqrtf(var + 1e-5f);
        const int f0 = tid * 2, f1 = tid * 2 + 1;
        const float o0 = (v.x - mu) * rstd * gamma[f0] + beta[f0];
        const float o1 = (v.y - mu) * rstd * gamma[f1] + beta[f1] + 1.0f;  // pe[0] = (0,1,0,1,..)
        half2v o; o.x = (half_t)o0; o.y = (half_t)o1;
        ((half2v*)(xo + (size_t)row * FDIM))[tid] = o;
    } else {
        const int idx = blockIdx.x - 2048;          // [0,192)
        const int k0 = (idx & 7) * 64;
        const int h  = (idx >> 3) & 7;
        const int z  = idx >> 6;
        const float* W = ((z == 0) ? Wq : (z == 1) ? Wk : Wv) + (size_t)h * FDIM * HD;
        __shared__ float Ls[64][65];
        {
            const int kk = tid >> 2, dg = (tid & 3) * 16;
            #pragma unroll
            for (int j = 0; j < 4; ++j) {
                const float4 w = *(const float4*)(W + (size_t)(k0 + kk) * HD + dg + j * 4);
                Ls[kk][dg + j * 4 + 0] = w.x; Ls[kk][dg + j * 4 + 1] = w.y;
                Ls[kk][dg + j * 4 + 2] = w.z; Ls[kk][dg + j * 4 + 3] = w.w;
            }
        }
        __syncthreads();
        {
            const int d = tid >> 2, kg = (tid & 3) * 16;
            half8v t0, t1;
            #pragma unroll
            for (int j = 0; j < 8; ++j) t0[j] = (half_t)Ls[kg + j][d];
            #pragma unroll
            for (int j = 0; j < 8; ++j) t1[j] = (half_t)Ls[kg + 8 + j][d];
            half_t* dst = WT + ((size_t)(z * NH + h) * HD + d) * FDIM + k0 + kg;
            *(half8v*)dst = t0;
            *(half8v*)(dst + 8) = t1;
        }
    }
}

// ---------------- Kernel 2: QKV projections, 128-row m-tile, LDS-free MFMA ----------------
// grid = (16 m-tiles of 128, 8 heads, 3 z). Each wave: 32 rows (2 rg of 16).
__global__ __launch_bounds__(256) void qkv_kernel(const half_t* __restrict__ xh,
                                                  const half_t* __restrict__ WT,
                                                  half_t* __restrict__ Qo,
                                                  half_t* __restrict__ Ko,
                                                  half_t* __restrict__ VTo) {
    const int ms0 = blockIdx.x * 128;
    const int h   = blockIdx.y, z = blockIdx.z;
    const half_t* Wt = WT + (size_t)(z * NH + h) * HD * FDIM;   // [64][512]

    const int tid = threadIdx.x;
    const int wv = tid >> 6, lane = tid & 63;
    const int lo = lane & 15, qq = lane >> 4;

    float4v acc[2][4];
    #pragma unroll
    for (int rg = 0; rg < 2; ++rg)
        #pragma unroll
        for (int cg = 0; cg < 4; ++cg) acc[rg][cg] = (float4v){0.f, 0.f, 0.f, 0.f};

    const half_t* ar[2];
    ar[0] = xh + (size_t)(ms0 + wv * 32 + lo) * FDIM + qq * 8;
    ar[1] = ar[0] + 16 * FDIM;
    const half_t* wrow[4];
    #pragma unroll
    for (int cg = 0; cg < 4; ++cg) wrow[cg] = Wt + (size_t)(cg * 16 + lo) * FDIM + qq * 8;

    half8v a_c[2][2], b_c[4][2];
    #pragma unroll
    for (int rg = 0; rg < 2; ++rg) { a_c[rg][0] = *(const half8v*)(ar[rg]); a_c[rg][1] = *(const half8v*)(ar[rg] + 32); }
    #pragma unroll
    for (int cg = 0; cg < 4; ++cg) { b_c[cg][0] = *(const half8v*)(wrow[cg]); b_c[cg][1] = *(const half8v*)(wrow[cg] + 32); }

    for (int k0 = 0; k0 < FDIM; k0 += 64) {
        const int kn0 = (k0 + 64 < FDIM) ? k0 + 64 : 0;
        const int kn1 = (k0 + 96 < FDIM) ? k0 + 96 : 0;
        half8v a_n[2][2], b_n[4][2];
        #pragma unroll
        for (int rg = 0; rg < 2; ++rg) { a_n[rg][0] = *(const half8v*)(ar[rg] + kn0); a_n[rg][1] = *(const half8v*)(ar[rg] + kn1); }
        #pragma unroll
        for (int cg = 0; cg < 4; ++cg) { b_n[cg][0] = *(const half8v*)(wrow[cg] + kn0); b_n[cg][1] = *(const half8v*)(wrow[cg] + kn1); }
        #pragma unroll
        for (int kh = 0; kh < 2; ++kh)
            #pragma unroll
            for (int rg = 0; rg < 2; ++rg)
                #pragma unroll
                for (int cg = 0; cg < 4; ++cg)
                    acc[rg][cg] = MFMA16(a_c[rg][kh], b_c[cg][kh], acc[rg][cg]);
        #pragma unroll
        for (int rg = 0; rg < 2; ++rg) { a_c[rg][0] = a_n[rg][0]; a_c[rg][1] = a_n[rg][1]; }
        #pragma unroll
        for (int cg = 0; cg < 4; ++cg) { b_c[cg][0] = b_n[cg][0]; b_c[cg][1] = b_n[cg][1]; }
    }

    if (z < 2) {
        half_t* Co = ((z == 0) ? Qo : Ko) + (size_t)h * S_LEN * HD;
        #pragma unroll
        for (int rg = 0; rg < 2; ++rg)
            #pragma unroll
            for (int cg = 0; cg < 4; ++cg)
                #pragma unroll
                for (int r = 0; r < 4; ++r)
                    Co[(size_t)(ms0 + wv * 32 + rg * 16 + qq * 4 + r) * HD + cg * 16 + lo] =
                        (half_t)acc[rg][cg][r];
    } else {
        __shared__ float Ls[128][65];
        #pragma unroll
        for (int rg = 0; rg < 2; ++rg)
            #pragma unroll
            for (int cg = 0; cg < 4; ++cg)
                #pragma unroll
                for (int r = 0; r < 4; ++r)
                    Ls[wv * 32 + rg * 16 + qq * 4 + r][cg * 16 + lo] = acc[rg][cg][r];
        __syncthreads();
        const int d = tid & 63, sg = tid >> 6;   // 4 s-chunks of 32
        half_t* dst = VTo + (size_t)(h * HD + d) * S_LEN + ms0 + sg * 32;
        #pragma unroll
        for (int c = 0; c < 4; ++c) {
            half8v t;
            #pragma unroll
            for (int j = 0; j < 8; ++j) t[j] = (half_t)Ls[sg * 32 + c * 8 + j][d];
            *(half8v*)(dst + c * 8) = t;
        }
    }
}

// ---------------- Kernel 3: attention core — 32 q-rows/block, t-split, raw-E export ----------------
// grid = (64 q-tiles of 32, 8 heads, 2 t-halves of 1024), 256 thr = 4 waves (256-t strips).
// S^T = K·Q^T (two q-halves A,B); online per-q max; P^T via shuffles; O^T = V^T·P^T.
__global__ __launch_bounds__(256) void attn2_kernel(const half_t* __restrict__ Qw,
                                                    const half_t* __restrict__ Kw,
                                                    const half_t* __restrict__ VT,
                                                    unsigned short* __restrict__ Praw,
                                                    half_t* __restrict__ Op,
                                                    float* __restrict__ mp,
                                                    float* __restrict__ lp) {
    const int s0 = blockIdx.x * 32;
    const int h  = blockIdx.y;
    const int z  = blockIdx.z;
    const half_t* Qh = Qw + (size_t)h * S_LEN * HD;
    const half_t* Kh = Kw + (size_t)h * S_LEN * HD;
    const half_t* Vt = VT + (size_t)h * (size_t)HD * S_LEN;

    __shared__ float Osh[4][32][65];
    __shared__ float lsh[4][32];
    __shared__ float msh[4][32];

    const int tid = threadIdx.x;
    const int wv = tid >> 6, lane = tid & 63;
    const int lo = lane & 15, qq = lane >> 4;
    const int tb = z * 1024 + wv * 256;

    const half8v qA0 = *(const half8v*)(Qh + (size_t)(s0 + lo) * HD + qq * 8);
    const half8v qA1 = *(const half8v*)(Qh + (size_t)(s0 + lo) * HD + 32 + qq * 8);
    const half8v qB0 = *(const half8v*)(Qh + (size_t)(s0 + 16 + lo) * HD + qq * 8);
    const half8v qB1 = *(const half8v*)(Qh + (size_t)(s0 + 16 + lo) * HD + 32 + qq * 8);

    float4v accA[4], accB[4];
    #pragma unroll
    for (int dt = 0; dt < 4; ++dt) {
        accA[dt] = (float4v){0.f, 0.f, 0.f, 0.f};
        accB[dt] = (float4v){0.f, 0.f, 0.f, 0.f};
    }
    float mA = 0.f, mB = 0.f, lA = 0.f, lB = 0.f;

    const int srcLow  = lo + ((qq & 1) * 2) * 16;
    const int srcHigh = srcLow + 16;
    const bool sel1 = (qq >> 1) != 0;

    unsigned short* prA = Praw + ((size_t)h << 22) + (size_t)(s0 + lo) * S_LEN + qq * 4;
    unsigned short* prB = prA + 16 * S_LEN;

    half8v kc[4];
    {
        const half_t* kp0 = Kh + (size_t)(tb + lo) * HD;
        const half_t* kp1 = Kh + (size_t)(tb + 16 + lo) * HD;
        kc[0] = *(const half8v*)(kp0 + qq * 8);
        kc[1] = *(const half8v*)(kp0 + 32 + qq * 8);
        kc[2] = *(const half8v*)(kp1 + qq * 8);
        kc[3] = *(const half8v*)(kp1 + 32 + qq * 8);
    }

    for (int ps = 0; ps < 8; ++ps) {
        const int Tg  = tb + ps * 32;
        const int Tgn = tb + ((ps < 7) ? ps + 1 : ps) * 32;
        // K prefetch (next step) + V for this step, both issued up front
        half8v kn[4], vc[4];
        {
            const half_t* kp0 = Kh + (size_t)(Tgn + lo) * HD;
            const half_t* kp1 = Kh + (size_t)(Tgn + 16 + lo) * HD;
            kn[0] = *(const half8v*)(kp0 + qq * 8);
            kn[1] = *(const half8v*)(kp0 + 32 + qq * 8);
            kn[2] = *(const half8v*)(kp1 + qq * 8);
            kn[3] = *(const half8v*)(kp1 + 32 + qq * 8);
            #pragma unroll
            for (int dt = 0; dt < 4; ++dt)
                vc[dt] = *(const half8v*)(Vt + (size_t)(dt * 16 + lo) * S_LEN + Tg + qq * 8);
        }
        // QK for both q-halves
        float4v c0A = (float4v){0.f, 0.f, 0.f, 0.f};
        c0A = MFMA16(kc[0], qA0, c0A); c0A = MFMA16(kc[1], qA1, c0A);
        float4v c1A = (float4v){0.f, 0.f, 0.f, 0.f};
        c1A = MFMA16(kc[2], qA0, c1A); c1A = MFMA16(kc[3], qA1, c1A);
        float4v c0B = (float4v){0.f, 0.f, 0.f, 0.f};
        c0B = MFMA16(kc[0], qB0, c0B); c0B = MFMA16(kc[1], qB1, c0B);
        float4v c1B = (float4v){0.f, 0.f, 0.f, 0.f};
        c1B = MFMA16(kc[2], qB0, c1B); c1B = MFMA16(kc[3], qB1, c1B);

        const int dd0 = s0 - Tg;
        const bool nA0 = (dd0 > -40) && (dd0 < 40);
        const bool nA1 = (dd0 - 16 > -40) && (dd0 - 16 < 40);
        const bool nB0 = (dd0 + 16 > -40) && (dd0 + 16 < 40);
        const bool nB1 = nA0;
        float S0A[4], S1A[4], S0B[4], S1B[4];
        #pragma unroll
        for (int r = 0; r < 4; ++r) {
            const int t0 = Tg + qq * 4 + r, t1 = t0 + 16;
            float sa0 = c0A[r] * 0.125f;
            if (nA0) { const float d = (float)(s0 + lo - t0); sa0 += __expf(-0.5f * d * d); }
            float sa1 = c1A[r] * 0.125f;
            if (nA1) { const float d = (float)(s0 + lo - t1); sa1 += __expf(-0.5f * d * d); }
            float sb0 = c0B[r] * 0.125f;
            if (nB0) { const float d = (float)(s0 + 16 + lo - t0); sb0 += __expf(-0.5f * d * d); }
            float sb1 = c1B[r] * 0.125f;
            if (nB1) { const float d = (float)(s0 + 16 + lo - t1); sb1 += __expf(-0.5f * d * d); }
            S0A[r] = sa0; S1A[r] = sa1; S0B[r] = sb0; S1B[r] = sb1;
        }
        // online max (per q; uniform across the 4 qq-lanes of each lo)
        float smA = fmaxf(fmaxf(fmaxf(S0A[0], S0A[1]), fmaxf(S0A[2], S0A[3])),
                          fmaxf(fmaxf(S1A[0], S1A[1]), fmaxf(S1A[2], S1A[3])));
        float smB = fmaxf(fmaxf(fmaxf(S0B[0], S0B[1]), fmaxf(S0B[2], S0B[3])),
                          fmaxf(fmaxf(S1B[0], S1B[1]), fmaxf(S1B[2], S1B[3])));
        smA = fmaxf(smA, __shfl_xor(smA, 16, 64));
        smA = fmaxf(smA, __shfl_xor(smA, 32, 64));
        smB = fmaxf(smB, __shfl_xor(smB, 16, 64));
        smB = fmaxf(smB, __shfl_xor(smB, 32, 64));
        const float mnA = fmaxf(mA, smA), mnB = fmaxf(mB, smB);
        const float alA = __expf(mA - mnA), alB = __expf(mB - mnB);
        mA = mnA; mB = mnB;
        float E0A[4], E1A[4], E0B[4], E1B[4];
        float lsA = 0.f, lsB = 0.f;
        #pragma unroll
        for (int r = 0; r < 4; ++r) {
            E0A[r] = __expf(S0A[r] - mnA); E1A[r] = __expf(S1A[r] - mnA);
            E0B[r] = __expf(S0B[r] - mnB); E1B[r] = __expf(S1B[r] - mnB);
            lsA += E0A[r] + E1A[r];
            lsB += E0B[r] + E1B[r];
        }
        lA = lA * alA + lsA;
        lB = lB * alB + lsB;
        #pragma unroll
        for (int dt = 0; dt < 4; ++dt)
            #pragma unroll
            for (int i = 0; i < 4; ++i) { accA[dt][i] *= alA; accB[dt][i] *= alB; }

        // raw e^s export (bf16)
        {
            const float emA = __expf(mnA), emB = __expf(mnB);
            ushort4v e0a, e1a, e0b, e1b;
            #pragma unroll
            for (int r = 0; r < 4; ++r) {
                e0a[r] = f2bf(E0A[r] * emA); e1a[r] = f2bf(E1A[r] * emA);
                e0b[r] = f2bf(E0B[r] * emB); e1b[r] = f2bf(E1B[r] * emB);
            }
            *(ushort4v*)(prA + Tg)      = e0a;
            *(ushort4v*)(prA + Tg + 16) = e1a;
            *(ushort4v*)(prB + Tg)      = e0b;
            *(ushort4v*)(prB + Tg + 16) = e1b;
        }

        // pack + shuffle-transpose -> P^T B-frags for both q-halves
        int pkA0, pkA1, pkA2, pkA3, pkB0, pkB1, pkB2, pkB3;
        {
            half2v p;
            p.x = (half_t)E0A[0]; p.y = (half_t)E0A[1]; pkA0 = __builtin_bit_cast(int, p);
            p.x = (half_t)E0A[2]; p.y = (half_t)E0A[3]; pkA1 = __builtin_bit_cast(int, p);
            p.x = (half_t)E1A[0]; p.y = (half_t)E1A[1]; pkA2 = __builtin_bit_cast(int, p);
            p.x = (half_t)E1A[2]; p.y = (half_t)E1A[3]; pkA3 = __builtin_bit_cast(int, p);
            p.x = (half_t)E0B[0]; p.y = (half_t)E0B[1]; pkB0 = __builtin_bit_cast(int, p);
            p.x = (half_t)E0B[2]; p.y = (half_t)E0B[3]; pkB1 = __builtin_bit_cast(int, p);
            p.x = (half_t)E1B[0]; p.y = (half_t)E1B[1]; pkB2 = __builtin_bit_cast(int, p);
            p.x = (half_t)E1B[2]; p.y = (half_t)E1B[3]; pkB3 = __builtin_bit_cast(int, p);
        }
        int4v biA, biB;
        {
            const int l0a = __shfl(pkA0, srcLow, 64),  l0b = __shfl(pkA2, srcLow, 64);
            const int l1a = __shfl(pkA1, srcLow, 64),  l1b = __shfl(pkA3, srcLow, 64);
            const int h0a = __shfl(pkA0, srcHigh, 64), h0b = __shfl(pkA2, srcHigh, 64);
            const int h1a = __shfl(pkA1, srcHigh, 64), h1b = __shfl(pkA3, srcHigh, 64);
            biA[0] = sel1 ? l0b : l0a;
            biA[1] = sel1 ? l1b : l1a;
            biA[2] = sel1 ? h0b : h0a;
            biA[3] = sel1 ? h1b : h1a;
        }
        {
            const int l0a = __shfl(pkB0, srcLow, 64),  l0b = __shfl(pkB2, srcLow, 64);
            const int l1a = __shfl(pkB1, srcLow, 64),  l1b = __shfl(pkB3, srcLow, 64);
            const int h0a = __shfl(pkB0, srcHigh, 64), h0b = __shfl(pkB2, srcHigh, 64);
            const int h1a = __shfl(pkB1, srcHigh, 64), h1b = __shfl(pkB3, srcHigh, 64);
            biB[0] = sel1 ? l0b : l0a;
            biB[1] = sel1 ? l1b : l1a;
            biB[2] = sel1 ? h0b : h0a;
            biB[3] = sel1 ? h1b : h1a;
        }
        const half8v bpA = __builtin_bit_cast(half8v, biA);
        const half8v bpB = __builtin_bit_cast(half8v, biB);
        #pragma unroll
        for (int dt = 0; dt < 4; ++dt) {
            accA[dt] = MFMA16(vc[dt], bpA, accA[dt]);
            accB[dt] = MFMA16(vc[dt], bpB, accB[dt]);
        }
        #pragma unroll
        for (int i = 0; i < 4; ++i) kc[i] = kn[i];
    }

    lA += __shfl_xor(lA, 16, 64); lA += __shfl_xor(lA, 32, 64);
    lB += __shfl_xor(lB, 16, 64); lB += __shfl_xor(lB, 32, 64);
    if (qq == 0) {
        lsh[wv][lo] = lA;      msh[wv][lo] = mA;
        lsh[wv][16 + lo] = lB; msh[wv][16 + lo] = mB;
    }
    #pragma unroll
    for (int dt = 0; dt < 4; ++dt)
        #pragma unroll
        for (int r = 0; r < 4; ++r) {
            Osh[wv][lo][dt * 16 + qq * 4 + r]      = accA[dt][r];
            Osh[wv][16 + lo][dt * 16 + qq * 4 + r] = accB[dt][r];
        }
    __syncthreads();

    // in-block merge across 4 waves -> UNNORMALIZED partial (M, L, O-f16) for this z-half
    #pragma unroll
    for (int p = 0; p < 2; ++p) {
        const int q = p * 16 + (tid >> 4), dg = tid & 15;
        const float m0 = msh[0][q], m1 = msh[1][q], m2 = msh[2][q], m3 = msh[3][q];
        const float M = fmaxf(fmaxf(m0, m1), fmaxf(m2, m3));
        const float f0 = __expf(m0 - M), f1 = __expf(m1 - M);
        const float f2 = __expf(m2 - M), f3 = __expf(m3 - M);
        const float L = lsh[0][q] * f0 + lsh[1][q] * f1 + lsh[2][q] * f2 + lsh[3][q] * f3;
        half4v o;
        #pragma unroll
        for (int i = 0; i < 4; ++i) {
            const float ov = Osh[0][q][dg * 4 + i] * f0 + Osh[1][q][dg * 4 + i] * f1 +
                             Osh[2][q][dg * 4 + i] * f2 + Osh[3][q][dg * 4 + i] * f3;
            o[i] = (half_t)ov;
        }
        const size_t pidx = (size_t)(z * NH + h) * S_LEN + s0 + q;
        *(half4v*)(Op + pidx * HD + dg * 4) = o;
        if (dg == 0) { mp[pidx] = M; lp[pidx] = L; }
    }
}

// ---------------- Kernel 4: merge partials + mean_weights, one block per q-row ----------------
__global__ __launch_bounds__(256) void meanmerge_kernel(const half_t* __restrict__ Op,
                                                        const float* __restrict__ mp,
                                                        const float* __restrict__ lp,
                                                        const unsigned short* __restrict__ Praw,
                                                        float* __restrict__ out) {
    const int q = blockIdx.x;
    const int tid = threadIdx.x;
    __shared__ float lish[NH];
    {
        const int h = tid >> 5, t32 = tid & 31;
        const size_t i0 = (size_t)h * S_LEN + q;
        const size_t i1 = (size_t)(NH + h) * S_LEN + q;
        const float m0 = mp[i0], m1 = mp[i1];
        const float M = fmaxf(m0, m1);
        const float f0 = __expf(m0 - M), f1 = __expf(m1 - M);
        const float L = lp[i0] * f0 + lp[i1] * f1;
        const float inv = 1.0f / L;
        if (t32 == 0) lish[h] = __expf(-M) * inv;
        const int d = t32 * 2;
        const half2v o0 = *(const half2v*)(Op + i0 * HD + d);
        const half2v o1 = *(const half2v*)(Op + i1 * HD + d);
        float2 o;
        o.x = ((float)o0.x * f0 + (float)o1.x * f1) * inv;
        o.y = ((float)o0.y * f0 + (float)o1.y * f1) * inv;
        *(float2*)(out + (size_t)q * FDIM + h * HD + d) = o;
    }
    __syncthreads();
    {
        const int idx = tid * 8;
        float acc[8] = {0.f, 0.f, 0.f, 0.f, 0.f, 0.f, 0.f, 0.f};
        #pragma unroll
        for (int h = 0; h < NH; ++h) {
            const uint4 u = *(const uint4*)(Praw + ((size_t)h << 22) + (size_t)q * S_LEN + idx);
            const float li = lish[h];
            const unsigned int uu[4] = {u.x, u.y, u.z, u.w};
            #pragma unroll
            for (int j = 0; j < 4; ++j) {
                const float a = __builtin_bit_cast(float, uu[j] << 16);
                const float b = __builtin_bit_cast(float, uu[j] & 0xFFFF0000u);
                acc[2 * j]     += a * li;
                acc[2 * j + 1] += b * li;
            }
        }
        float* o = out + MH_ELEMS + (size_t)q * S_LEN + idx;
        *(float4*)o       = make_float4(acc[0] * 0.125f, acc[1] * 0.125f, acc[2] * 0.125f, acc[3] * 0.125f);
        *(float4*)(o + 4) = make_float4(acc[4] * 0.125f, acc[5] * 0.125f, acc[6] * 0.125f, acc[7] * 0.125f);
    }
}

extern "C" void kernel_launch(void* const* d_in, const int* in_sizes, int n_in,
                              void* d_out, int out_size, void* d_ws, size_t ws_size,
                              hipStream_t stream) {
    const float* x  = (const float*)d_in[0];
    const float* Wq = (const float*)d_in[1];
    const float* Wk = (const float*)d_in[2];
    const float* Wv = (const float*)d_in[3];
    const float* g  = (const float*)d_in[4];
    const float* b  = (const float*)d_in[5];
    float* out = (float*)d_out;
    char*  ws  = (char*)d_ws;

    half_t* Qh   = (half_t*)(ws);                            // [0, 2MB)
    half_t* Kh   = (half_t*)(ws + (2ull  << 20));            // [2, 4)
    half_t* VT   = (half_t*)(ws + (4ull  << 20));            // [4, 6)   [8][64][2048]
    half_t* xh   = (half_t*)(ws + (6ull  << 20));            // [6, 8)
    half_t* WT   = (half_t*)(ws + (8ull  << 20));            // [8, 9.5) [3][8][64][512]
    half_t* Op   = (half_t*)(ws + (10ull << 20));            // [10, 14) [2][8][2048][64]
    float*  mp   = (float*) (ws + (14ull << 20));            // 128 KB   [2][8][2048]
    float*  lp   = (float*) (ws + (14ull << 20) + (128ull << 10)); // 128 KB
    unsigned short* Praw = (unsigned short*)(ws + (16ull << 20));  // [16, 80) [8][2048][2048] bf16

    prep_kernel<<<2240, 256, 0, stream>>>(x, g, b, Wq, Wk, Wv, xh, WT);
    qkv_kernel<<<dim3(16, 8, 3), 256, 0, stream>>>(xh, WT, Qh, Kh, VT);
    attn2_kernel<<<dim3(64, 8, 2), 256, 0, stream>>>(Qh, Kh, VT, Praw, Op, mp, lp);
    meanmerge_kernel<<<S_LEN, 256, 0, stream>>>(Op, mp, lp, Praw, out);
}